// Round 1
// baseline (743.768 us; speedup 1.0000x reference)
//
#include <hip/hip_runtime.h>
#include <math.h>

// Problem constants (fixed by reference)
#define Z 2
#define NPT 256     // points per batch
#define CHN 16      // channels
#define NH 2        // heads
#define NBK 10      // key/conv radial basis
#define HD 100      // radial hidden width
#define NBV 3       // value radial basis
#define BT 8        // b-tile in attention kernel
#define CBT 16      // b-tile in conv kernel

__device__ __forceinline__ float swishf(float x) {
    return x / (1.0f + __expf(-x));
}

// ---------------------------------------------------------------------------
// Kernel 1: Gq[z,h,a,m,j] = sum_i Kf[h][m][i*16+j] * q[z,h,a,i],
//           q[z,h,a,i] = sum_c f[z,a,c] * Wq[h][i][c]
// grid = Z*NH*NPT blocks, 256 threads
// ---------------------------------------------------------------------------
__global__ __launch_bounds__(256)
void gq_kernel(const float* __restrict__ f, const float* __restrict__ Wq,
               const float* __restrict__ Kf, float* __restrict__ Gq) {
    int id = blockIdx.x;            // ((z*NH + h)*NPT + a)
    int a  = id & 255;
    int zh = id >> 8;
    int h  = zh & 1;
    int z  = zh >> 1;
    int t  = threadIdx.x;
    __shared__ float s_fa[CHN];
    __shared__ float s_q[CHN];
    if (t < CHN) s_fa[t] = f[(z*NPT + a)*CHN + t];
    __syncthreads();
    if (t < CHN) {
        float s = 0.f;
        const float* wq = Wq + (h*CHN + t)*CHN;   // Wq[h][o][i]
        #pragma unroll
        for (int i = 0; i < CHN; ++i) s += s_fa[i] * wq[i];
        s_q[t] = s;
    }
    __syncthreads();
    const float* kf = Kf + h*HD*CHN*CHN;          // [HD][256]
    float* gq = Gq + (size_t)id*HD*CHN;           // layout [m][j]
    for (int idx = t; idx < HD*CHN; idx += 256) {
        int m = idx >> 4, j = idx & 15;
        float s = 0.f;
        #pragma unroll
        for (int i = 0; i < CHN; ++i) s += kf[m*256 + i*16 + j] * s_q[i];
        gq[idx] = s;
    }
}

// ---------------------------------------------------------------------------
// Kernel 2: attention with online softmax + U-factorized value path.
// One block per (z,a); loop over b in tiles of BT.
// ---------------------------------------------------------------------------
__global__ __launch_bounds__(256)
void attn_kernel(const float* __restrict__ f, const float* __restrict__ xyz,
                 const float* __restrict__ K0, const float* __restrict__ K1,
                 const float* __restrict__ V0, const float* __restrict__ Vf,
                 const float* __restrict__ Gq, float* __restrict__ attn_out) {
    int za = blockIdx.x;            // z*NPT + a
    int z = za >> 8, a = za & 255;
    int t = threadIdx.x;

    __shared__ float s_xyz[3];
    __shared__ float s_b10[BT][NBK];
    __shared__ float s_b3[BT][NBV];
    __shared__ float s_f[BT][CHN];
    __shared__ float s_h1T[NH*HD*BT];     // [(h*HD+n)*BT + bt]  (key hidden1, transposed)
    __shared__ float s_h1vT[NH*HD*BT];    // value hidden1, transposed
    __shared__ float s_h2[NH*BT*HD];      // [(h*BT+bt)*HD + m]
    __shared__ float s_gq[NH*CHN*HD];     // [(h*16+j)*HD + m]
    __shared__ float s_U[NH*CHN*HD];      // [(h*16+j)*HD + m]
    __shared__ float s_score[NH][BT];
    __shared__ float s_e[NH][BT];
    __shared__ float s_alpha[NH];
    __shared__ float s_m[NH], s_l[NH];
    __shared__ float s_part[NH][CHN];

    if (t < 3) s_xyz[t] = xyz[za*3 + t];
    if (t < NH) { s_m[t] = -1e30f; s_l[t] = 0.f; }
    {   // load Gq for this (z,a), both heads, into [j][m] layout; zero U
        const float* gq0 = Gq + (size_t)((z*NH + 0)*NPT + a)*HD*CHN;
        const float* gq1 = Gq + (size_t)((z*NH + 1)*NPT + a)*HD*CHN;
        for (int idx = t; idx < CHN*HD; idx += 256) {
            int jj = idx / HD, m = idx % HD;
            s_gq[idx]          = gq0[m*16 + jj];
            s_gq[CHN*HD + idx] = gq1[m*16 + jj];
            s_U[idx] = 0.f;
            s_U[CHN*HD + idx] = 0.f;
        }
    }
    __syncthreads();

    for (int b0 = 0; b0 < NPT; b0 += BT) {
        // --- phase 0: distances, cosine bases, neighbor features ---
        if (t < BT*CHN) {  // 128 threads
            int bt = t >> 4, j = t & 15;
            s_f[bt][j] = f[(z*NPT + b0 + bt)*CHN + j];
        }
        if (t < BT) {
            int b = b0 + t;
            float dx = xyz[(z*NPT+b)*3+0] - s_xyz[0];
            float dy = xyz[(z*NPT+b)*3+1] - s_xyz[1];
            float dz = xyz[(z*NPT+b)*3+2] - s_xyz[2];
            float d = sqrtf(dx*dx + dy*dy + dz*dz + 1e-12f);
            #pragma unroll
            for (int n = 0; n < NBK; ++n) {
                float diff = (d - n*(5.0f/9.0f)) * 1.8f;
                s_b10[t][n] = (fabsf(diff) < 1.0f) ? __cosf(1.57079632679f*diff) : 0.f;
            }
            #pragma unroll
            for (int n = 0; n < NBV; ++n) {
                float diff = (d - n*2.5f) * 0.4f;
                s_b3[t][n] = (fabsf(diff) < 1.0f) ? __cosf(1.57079632679f*diff) : 0.f;
            }
        }
        __syncthreads();
        // --- phase B: first hidden layers (key h1, value h1v) ---
        if (t < NH*HD) {
            int h = t / HD, m = t % HD;
            float w[NBK];
            #pragma unroll
            for (int n = 0; n < NBK; ++n) w[n] = K0[(h*NBK + n)*HD + m];
            float* dst = &s_h1T[(h*HD + m)*BT];
            #pragma unroll
            for (int bt = 0; bt < BT; ++bt) {
                float s = 0.f;
                #pragma unroll
                for (int n = 0; n < NBK; ++n) s += s_b10[bt][n] * w[n];
                dst[bt] = swishf(s);
            }
            float wv[NBV];
            #pragma unroll
            for (int n = 0; n < NBV; ++n) wv[n] = V0[(h*NBV + n)*HD + m];
            float* dstv = &s_h1vT[(h*HD + m)*BT];
            #pragma unroll
            for (int bt = 0; bt < BT; ++bt) {
                float s = 0.f;
                #pragma unroll
                for (int n = 0; n < NBV; ++n) s += s_b3[bt][n] * wv[n];
                dstv[bt] = swishf(s);
            }
        }
        __syncthreads();
        // --- phase C: h2 = swish(h1 @ K1), bt-vectorized per (h,m) thread ---
        if (t < NH*HD) {
            int h = t / HD, m = t % HD;
            float acc[BT];
            #pragma unroll
            for (int bt = 0; bt < BT; ++bt) acc[bt] = 0.f;
            const float* k1 = K1 + h*HD*HD + m;        // K1[h][n][m]
            const float4* h1p = (const float4*)&s_h1T[h*HD*BT];
            for (int n = 0; n < HD; ++n) {
                float w = k1[n*HD];
                float4 x0 = h1p[n*2+0];
                float4 x1 = h1p[n*2+1];
                acc[0] += x0.x*w; acc[1] += x0.y*w; acc[2] += x0.z*w; acc[3] += x0.w*w;
                acc[4] += x1.x*w; acc[5] += x1.y*w; acc[6] += x1.z*w; acc[7] += x1.w*w;
            }
            #pragma unroll
            for (int bt = 0; bt < BT; ++bt)
                s_h2[(h*BT + bt)*HD + m] = swishf(acc[bt]);
        }
        __syncthreads();
        // --- phase D: scores; 16 threads cooperate per (h,bt) ---
        {
            int g = t >> 4;          // 0..15 : h = g>>3, bt = g&7
            int s16 = t & 15;
            int h = g >> 3, bt = g & 7;
            float part = 0.f;
            const float* gq = &s_gq[h*CHN*HD];
            const float* h2 = &s_h2[(h*BT + bt)*HD];
            for (int m = s16; m < HD; m += 16) {
                float gsum = 0.f;
                #pragma unroll
                for (int j = 0; j < CHN; ++j) gsum += gq[j*HD + m] * s_f[bt][j];
                part += h2[m] * gsum;
            }
            part += __shfl_down(part, 8, 16);
            part += __shfl_down(part, 4, 16);
            part += __shfl_down(part, 2, 16);
            part += __shfl_down(part, 1, 16);
            if (s16 == 0) s_score[h][bt] = part * (1.0f/16.0f);
        }
        __syncthreads();
        // --- phase E1: online-softmax running update ---
        if (t < NH) {
            int h = t;
            float mold = s_m[h];
            float tmax = -1e30f;
            #pragma unroll
            for (int bt = 0; bt < BT; ++bt) tmax = fmaxf(tmax, s_score[h][bt]);
            float mnew = fmaxf(mold, tmax);
            float alpha = __expf(mold - mnew);
            float lsum = 0.f;
            #pragma unroll
            for (int bt = 0; bt < BT; ++bt) {
                float e = __expf(s_score[h][bt] - mnew);
                s_e[h][bt] = e;
                lsum += e;
            }
            s_l[h] = s_l[h]*alpha + lsum;
            s_m[h] = mnew;
            s_alpha[h] = alpha;
        }
        __syncthreads();
        // --- phase E2: U[m,j] = alpha*U + sum_bt e[bt]*h1v[bt,m]*f[bt,j] ---
        if (t < NH*HD) {
            int h = t / HD, m = t % HD;
            float alpha = s_alpha[h];
            float t1[BT];
            const float* h1v = &s_h1vT[(h*HD + m)*BT];
            #pragma unroll
            for (int bt = 0; bt < BT; ++bt) t1[bt] = s_e[h][bt] * h1v[bt];
            float* U = &s_U[h*CHN*HD + m];
            #pragma unroll
            for (int j = 0; j < CHN; ++j) {
                float s = 0.f;
                #pragma unroll
                for (int bt = 0; bt < BT; ++bt) s += t1[bt] * s_f[bt][j];
                U[j*HD] = U[j*HD]*alpha + s;
            }
        }
        __syncthreads();
    }
    // --- epilogue: out[a,i] = sum_h (1/l_h) sum_{m,j} U[h][j][m]*Vf[h][m][i*16+j]
    if (t < NH*CHN) {
        int h = t >> 4, i = t & 15;
        const float* vf = Vf + h*HD*CHN*CHN;
        const float* U  = &s_U[h*CHN*HD];
        float s = 0.f;
        for (int m = 0; m < HD; ++m) {
            #pragma unroll
            for (int j = 0; j < CHN; ++j) s += U[j*HD + m] * vf[m*256 + i*16 + j];
        }
        s_part[h][i] = s / s_l[h];
    }
    __syncthreads();
    if (t < CHN) attn_out[za*CHN + t] = s_part[0][t] + s_part[1][t];
}

// ---------------------------------------------------------------------------
// Kernel 3: final equivariant conv, same U-factorization against attn_out.
// One block per (z,a), 128 threads; b in tiles of CBT.
// ---------------------------------------------------------------------------
__global__ __launch_bounds__(128)
void conv_kernel(const float* __restrict__ xyz, const float* __restrict__ C0,
                 const float* __restrict__ C1, const float* __restrict__ Cf,
                 const float* __restrict__ attn_out, float* __restrict__ out) {
    int za = blockIdx.x;
    int z = za >> 8;
    int t = threadIdx.x;
    __shared__ float s_xyz[3];
    __shared__ float s_b10[CBT][NBK];
    __shared__ float s_o[CBT][CHN];
    __shared__ float s_h1T[HD*CBT];     // [n*CBT + bt]
    __shared__ float s_U[CHN*HD];       // [j*HD + m]
    if (t < 3) s_xyz[t] = xyz[za*3 + t];
    for (int idx = t; idx < CHN*HD; idx += 128) s_U[idx] = 0.f;
    __syncthreads();
    for (int b0 = 0; b0 < NPT; b0 += CBT) {
        if (t < CBT) {
            int b = b0 + t;
            float dx = xyz[(z*NPT+b)*3+0] - s_xyz[0];
            float dy = xyz[(z*NPT+b)*3+1] - s_xyz[1];
            float dz = xyz[(z*NPT+b)*3+2] - s_xyz[2];
            float d = sqrtf(dx*dx + dy*dy + dz*dz + 1e-12f);
            #pragma unroll
            for (int n = 0; n < NBK; ++n) {
                float diff = (d - n*(5.0f/9.0f)) * 1.8f;
                s_b10[t][n] = (fabsf(diff) < 1.0f) ? __cosf(1.57079632679f*diff) : 0.f;
            }
        }
        for (int idx = t; idx < CBT*CHN; idx += 128) {
            int bt = idx >> 4, j = idx & 15;
            s_o[bt][j] = attn_out[(z*NPT + b0 + bt)*CHN + j];
        }
        __syncthreads();
        if (t < HD) {
            int m = t;
            float w[NBK];
            #pragma unroll
            for (int n = 0; n < NBK; ++n) w[n] = C0[n*HD + m];
            float* dst = &s_h1T[m*CBT];
            #pragma unroll
            for (int bt = 0; bt < CBT; ++bt) {
                float s = 0.f;
                #pragma unroll
                for (int n = 0; n < NBK; ++n) s += s_b10[bt][n]*w[n];
                dst[bt] = swishf(s);
            }
        }
        __syncthreads();
        if (t < HD) {
            int m = t;
            float acc[CBT];
            #pragma unroll
            for (int bt = 0; bt < CBT; ++bt) acc[bt] = 0.f;
            const float* c1 = C1 + m;                // C1[n][m]
            const float4* h1p = (const float4*)s_h1T;
            for (int n = 0; n < HD; ++n) {
                float w = c1[n*HD];
                float4 x0 = h1p[n*4+0]; float4 x1 = h1p[n*4+1];
                float4 x2 = h1p[n*4+2]; float4 x3 = h1p[n*4+3];
                acc[0]+=x0.x*w;  acc[1]+=x0.y*w;  acc[2]+=x0.z*w;  acc[3]+=x0.w*w;
                acc[4]+=x1.x*w;  acc[5]+=x1.y*w;  acc[6]+=x1.z*w;  acc[7]+=x1.w*w;
                acc[8]+=x2.x*w;  acc[9]+=x2.y*w;  acc[10]+=x2.z*w; acc[11]+=x2.w*w;
                acc[12]+=x3.x*w; acc[13]+=x3.y*w; acc[14]+=x3.z*w; acc[15]+=x3.w*w;
            }
            #pragma unroll
            for (int bt = 0; bt < CBT; ++bt) acc[bt] = swishf(acc[bt]);
            #pragma unroll
            for (int j = 0; j < CHN; ++j) {
                float s = 0.f;
                #pragma unroll
                for (int bt = 0; bt < CBT; ++bt) s += acc[bt]*s_o[bt][j];
                s_U[j*HD + m] += s;
            }
        }
        __syncthreads();
    }
    if (t < CHN) {
        int i = t;
        float s = 0.f;
        for (int m = 0; m < HD; ++m) {
            #pragma unroll
            for (int j = 0; j < CHN; ++j) s += s_U[j*HD + m] * Cf[m*256 + i*16 + j];
        }
        out[za*CHN + i] = s;
    }
}

// ---------------------------------------------------------------------------
extern "C" void kernel_launch(void* const* d_in, const int* in_sizes, int n_in,
                              void* d_out, int out_size, void* d_ws, size_t ws_size,
                              hipStream_t stream) {
    const float* f   = (const float*)d_in[0];
    const float* xyz = (const float*)d_in[1];
    const float* Wq  = (const float*)d_in[2];
    const float* K0  = (const float*)d_in[3];
    const float* K1  = (const float*)d_in[4];
    const float* Kf  = (const float*)d_in[5];
    const float* V0  = (const float*)d_in[6];
    const float* Vf  = (const float*)d_in[7];
    const float* C0  = (const float*)d_in[8];
    const float* C1  = (const float*)d_in[9];
    const float* Cf  = (const float*)d_in[10];
    float* out  = (float*)d_out;
    float* Gq   = (float*)d_ws;                          // Z*NH*NPT*HD*CHN floats (6.55 MB)
    float* attn = Gq + (size_t)Z*NH*NPT*HD*CHN;          // Z*NPT*CHN floats

    gq_kernel  <<<Z*NH*NPT, 256, 0, stream>>>(f, Wq, Kf, Gq);
    attn_kernel<<<Z*NPT,    256, 0, stream>>>(f, xyz, K0, K1, V0, Vf, Gq, attn);
    conv_kernel<<<Z*NPT,    128, 0, stream>>>(xyz, C0, C1, Cf, attn, out);
}

// Round 2
// 384.627 us; speedup vs baseline: 1.9337x; 1.9337x over previous
//
#include <hip/hip_runtime.h>
#include <math.h>

// Problem constants (fixed by reference)
#define Z 2
#define NPT 256     // points per batch
#define CHN 16      // channels
#define NH 2        // heads
#define NBK 10      // key/conv radial basis
#define HD 100      // radial hidden width
#define NBV 3       // value radial basis
#define SCH 32      // b-chunk in score kernel
#define CCH 64      // b-chunk in conv partial kernel
#define NCHS (NPT/SCH)   // 8
#define NCHC (NPT/CCH)   // 4

__device__ __forceinline__ float swishf(float x) {
    return x / (1.0f + __expf(-x));
}

// ---------------------------------------------------------------------------
// Kernel 1: Gq[z,h,a,m,j] = sum_i Kf[h][m][i*16+j] * q[z,h,a,i],
//           q[z,h,a,i] = sum_c f[z,a,c] * Wq[h][i][c]
// grid = Z*NH*NPT blocks, 256 threads
// ---------------------------------------------------------------------------
__global__ __launch_bounds__(256)
void gq_kernel(const float* __restrict__ f, const float* __restrict__ Wq,
               const float* __restrict__ Kf, float* __restrict__ Gq) {
    int id = blockIdx.x;            // ((z*NH + h)*NPT + a)
    int a  = id & 255;
    int zh = id >> 8;
    int h  = zh & 1;
    int z  = zh >> 1;
    int t  = threadIdx.x;
    __shared__ float s_fa[CHN];
    __shared__ float s_q[CHN];
    if (t < CHN) s_fa[t] = f[(z*NPT + a)*CHN + t];
    __syncthreads();
    if (t < CHN) {
        float s = 0.f;
        const float* wq = Wq + (h*CHN + t)*CHN;   // Wq[h][o][i]
        #pragma unroll
        for (int i = 0; i < CHN; ++i) s += s_fa[i] * wq[i];
        s_q[t] = s;
    }
    __syncthreads();
    const float* kf = Kf + h*HD*CHN*CHN;          // [HD][256]
    float* gq = Gq + (size_t)id*HD*CHN;           // layout [m][j]
    for (int idx = t; idx < HD*CHN; idx += 256) {
        int m = idx >> 4, j = idx & 15;
        float s = 0.f;
        #pragma unroll
        for (int i = 0; i < CHN; ++i) s += kf[m*256 + i*16 + j] * s_q[i];
        gq[idx] = s;
    }
}

// ---------------------------------------------------------------------------
// Kernel 2: scores[z,h,a,b] for a 32-b chunk per block.
// grid = Z*NH*NPT*NCHS = 8192 blocks, 256 threads.
// Thread map for heavy phases: g = t>>7 (b half), m = t&127 (<100 active).
// ---------------------------------------------------------------------------
__global__ __launch_bounds__(256)
void score_kernel(const float* __restrict__ f, const float* __restrict__ xyz,
                  const float* __restrict__ K0, const float* __restrict__ K1,
                  const float* __restrict__ Gq, float* __restrict__ scores) {
    int id = blockIdx.x;             // (((z*NH+h)*NPT)+a)*NCHS + c
    int c  = id & (NCHS-1);
    int rest = id >> 3;              // (z*NH+h)*NPT + a
    int a  = rest & 255;
    int zh = rest >> 8;
    int h  = zh & 1;
    int z  = zh >> 1;
    int b0 = c * SCH;
    int t  = threadIdx.x;
    int g    = t >> 7;               // 0/1: bt 0..15 / 16..31
    int mloc = t & 127;

    __shared__ float s_xyz[3];
    __shared__ float s_b10[SCH][NBK];
    __shared__ float s_f[SCH][CHN];
    __shared__ float s_gq[HD*CHN];          // [m][j]
    __shared__ float s_h1[HD][SCH+4];       // [n][bt], +4 pad keeps 16B align
    __shared__ float s_ps[SCH][HD];         // [bt][m] partial score products

    if (t < 3) s_xyz[t] = xyz[(z*NPT + a)*3 + t];
    {   // stage Gq (already [m][j] in global)
        const float* gq = Gq + (size_t)rest*HD*CHN;
        for (int idx = t; idx < HD*CHN; idx += 256) s_gq[idx] = gq[idx];
    }
    for (int idx = t; idx < SCH*CHN; idx += 256) {
        int bt = idx >> 4, j = idx & 15;
        s_f[bt][j] = f[(z*NPT + b0 + bt)*CHN + j];
    }
    __syncthreads();
    if (t < SCH) {
        int b = b0 + t;
        float dx = xyz[(z*NPT+b)*3+0] - s_xyz[0];
        float dy = xyz[(z*NPT+b)*3+1] - s_xyz[1];
        float dz = xyz[(z*NPT+b)*3+2] - s_xyz[2];
        float d = sqrtf(dx*dx + dy*dy + dz*dz + 1e-12f);
        #pragma unroll
        for (int n = 0; n < NBK; ++n) {
            float diff = (d - n*(5.0f/9.0f)) * 1.8f;
            s_b10[t][n] = (fabsf(diff) < 1.0f) ? __cosf(1.57079632679f*diff) : 0.f;
        }
    }
    __syncthreads();
    // --- h1 = swish(basis @ K0): thread (n=mloc, g) does 16 bt's ---
    if (mloc < HD) {
        int n = mloc;
        float w[NBK];
        #pragma unroll
        for (int k = 0; k < NBK; ++k) w[k] = K0[(h*NBK + k)*HD + n];
        #pragma unroll
        for (int bl = 0; bl < 16; ++bl) {
            int btg = g*16 + bl;
            float s = 0.f;
            #pragma unroll
            for (int k = 0; k < NBK; ++k) s += s_b10[btg][k] * w[k];
            s_h1[n][btg] = swishf(s);
        }
    }
    __syncthreads();
    // --- h2 = swish(h1 @ K1); score partials ---
    if (mloc < HD) {
        int m = mloc;
        float gq[CHN];
        {
            const float4* gp = (const float4*)&s_gq[m*CHN];
            float4 g0 = gp[0], g1 = gp[1], g2 = gp[2], g3 = gp[3];
            gq[0]=g0.x; gq[1]=g0.y; gq[2]=g0.z; gq[3]=g0.w;
            gq[4]=g1.x; gq[5]=g1.y; gq[6]=g1.z; gq[7]=g1.w;
            gq[8]=g2.x; gq[9]=g2.y; gq[10]=g2.z; gq[11]=g2.w;
            gq[12]=g3.x; gq[13]=g3.y; gq[14]=g3.z; gq[15]=g3.w;
        }
        float acc[16];
        #pragma unroll
        for (int i = 0; i < 16; ++i) acc[i] = 0.f;
        const float* k1 = K1 + (size_t)h*HD*HD + m;     // K1[h][n][m]
        #pragma unroll 2
        for (int n = 0; n < HD; ++n) {
            float w = k1[n*HD];
            const float4* hp = (const float4*)&s_h1[n][g*16];
            float4 x0 = hp[0], x1 = hp[1], x2 = hp[2], x3 = hp[3];
            acc[0]+=x0.x*w;  acc[1]+=x0.y*w;  acc[2]+=x0.z*w;  acc[3]+=x0.w*w;
            acc[4]+=x1.x*w;  acc[5]+=x1.y*w;  acc[6]+=x1.z*w;  acc[7]+=x1.w*w;
            acc[8]+=x2.x*w;  acc[9]+=x2.y*w;  acc[10]+=x2.z*w; acc[11]+=x2.w*w;
            acc[12]+=x3.x*w; acc[13]+=x3.y*w; acc[14]+=x3.z*w; acc[15]+=x3.w*w;
        }
        #pragma unroll
        for (int bl = 0; bl < 16; ++bl) {
            int btg = g*16 + bl;
            float h2 = swishf(acc[bl]);
            const float4* fp = (const float4*)&s_f[btg][0];
            float4 f0 = fp[0], f1 = fp[1], f2 = fp[2], f3 = fp[3];
            float gf = gq[0]*f0.x + gq[1]*f0.y + gq[2]*f0.z + gq[3]*f0.w
                     + gq[4]*f1.x + gq[5]*f1.y + gq[6]*f1.z + gq[7]*f1.w
                     + gq[8]*f2.x + gq[9]*f2.y + gq[10]*f2.z + gq[11]*f2.w
                     + gq[12]*f3.x + gq[13]*f3.y + gq[14]*f3.z + gq[15]*f3.w;
            s_ps[btg][m] = h2 * gf;
        }
    }
    __syncthreads();
    if (t < SCH) {
        float s = 0.f;
        #pragma unroll 4
        for (int m = 0; m < HD; ++m) s += s_ps[t][m];
        scores[(size_t)rest*NPT + b0 + t] = s * (1.0f/16.0f);
    }
}

// ---------------------------------------------------------------------------
// Kernel 3a: row softmax, one wave per (z,h,a) row of 256 scores.
// ---------------------------------------------------------------------------
__global__ __launch_bounds__(64)
void softmax_kernel(const float* __restrict__ scores, float* __restrict__ p) {
    int row = blockIdx.x;            // (z*NH+h)*NPT + a
    int t = threadIdx.x;
    const float4* sp = (const float4*)(scores + (size_t)row*NPT);
    float4 v = sp[t];
    float mx = fmaxf(fmaxf(v.x, v.y), fmaxf(v.z, v.w));
    #pragma unroll
    for (int off = 1; off < 64; off <<= 1) mx = fmaxf(mx, __shfl_xor(mx, off));
    float e0 = __expf(v.x - mx), e1 = __expf(v.y - mx);
    float e2 = __expf(v.z - mx), e3 = __expf(v.w - mx);
    float s = e0 + e1 + e2 + e3;
    #pragma unroll
    for (int off = 1; off < 64; off <<= 1) s += __shfl_xor(s, off);
    float inv = 1.0f / s;
    float4 r; r.x = e0*inv; r.y = e1*inv; r.z = e2*inv; r.w = e3*inv;
    ((float4*)(p + (size_t)row*NPT))[t] = r;
}

// ---------------------------------------------------------------------------
// Kernel 3b: per (z,h,a): U[m,j] = sum_b p_b*h1v[b,m]*f[b,j]; contract Vf.
// grid = Z*NH*NPT = 1024 blocks, 256 threads. g = b-half, m = t&127.
// ---------------------------------------------------------------------------
__global__ __launch_bounds__(256)
void attn_value_kernel(const float* __restrict__ f, const float* __restrict__ xyz,
                       const float* __restrict__ V0, const float* __restrict__ Vf,
                       const float* __restrict__ p, float* __restrict__ attn_h) {
    int id = blockIdx.x;             // (z*NH+h)*NPT + a
    int a  = id & 255;
    int zh = id >> 8;
    int h  = zh & 1;
    int z  = zh >> 1;
    int t  = threadIdx.x;
    int g    = t >> 7;
    int mloc = t & 127;

    __shared__ float s_xyz[3];
    __shared__ float s_b3[NPT][NBV];
    __shared__ float s_f[NPT*CHN];
    __shared__ float s_p[NPT];
    __shared__ float s_U[HD][CHN+1];
    __shared__ float s_red[16][16];

    if (t < 3) s_xyz[t] = xyz[(z*NPT + a)*3 + t];
    __syncthreads();
    {
        int b = t;
        float dx = xyz[(z*NPT+b)*3+0] - s_xyz[0];
        float dy = xyz[(z*NPT+b)*3+1] - s_xyz[1];
        float dz = xyz[(z*NPT+b)*3+2] - s_xyz[2];
        float d = sqrtf(dx*dx + dy*dy + dz*dz + 1e-12f);
        #pragma unroll
        for (int k = 0; k < NBV; ++k) {
            float diff = (d - k*2.5f) * 0.4f;
            s_b3[b][k] = (fabsf(diff) < 1.0f) ? __cosf(1.57079632679f*diff) : 0.f;
        }
        s_p[b] = p[(size_t)id*NPT + b];
    }
    for (int idx = t; idx < NPT*CHN; idx += 256) s_f[idx] = f[z*NPT*CHN + idx];
    __syncthreads();

    float U[16];
    #pragma unroll
    for (int j = 0; j < 16; ++j) U[j] = 0.f;
    if (mloc < HD) {
        int m = mloc;
        float w0 = V0[(h*NBV+0)*HD + m];
        float w1 = V0[(h*NBV+1)*HD + m];
        float w2 = V0[(h*NBV+2)*HD + m];
        int bbase = g*128;
        for (int bb = 0; bb < 128; ++bb) {
            int b = bbase + bb;
            float hv = swishf(s_b3[b][0]*w0 + s_b3[b][1]*w1 + s_b3[b][2]*w2);
            float t1 = s_p[b] * hv;
            const float4* fp = (const float4*)&s_f[b*CHN];
            float4 f0 = fp[0], f1 = fp[1], f2 = fp[2], f3 = fp[3];
            U[0]+=t1*f0.x;  U[1]+=t1*f0.y;  U[2]+=t1*f0.z;  U[3]+=t1*f0.w;
            U[4]+=t1*f1.x;  U[5]+=t1*f1.y;  U[6]+=t1*f1.z;  U[7]+=t1*f1.w;
            U[8]+=t1*f2.x;  U[9]+=t1*f2.y;  U[10]+=t1*f2.z; U[11]+=t1*f2.w;
            U[12]+=t1*f3.x; U[13]+=t1*f3.y; U[14]+=t1*f3.z; U[15]+=t1*f3.w;
        }
    }
    if (g == 1 && mloc < HD) {
        #pragma unroll
        for (int j = 0; j < 16; ++j) s_U[mloc][j] = U[j];
    }
    __syncthreads();
    if (g == 0 && mloc < HD) {
        #pragma unroll
        for (int j = 0; j < 16; ++j) s_U[mloc][j] += U[j];
    }
    __syncthreads();
    {   // out_part[i] = sum_{m,j} U[m,j] * Vf[h][m][i*16+j]
        int i = t & 15, ms = t >> 4;
        float acc = 0.f;
        for (int m = ms; m < HD; m += 16) {
            const float* vf = Vf + ((size_t)h*HD + m)*256 + i*16;
            const float* Um = &s_U[m][0];
            #pragma unroll
            for (int j = 0; j < 16; ++j) acc += Um[j] * vf[j];
        }
        s_red[ms][i] = acc;
    }
    __syncthreads();
    if (t < 16) {
        float s = 0.f;
        #pragma unroll
        for (int ms = 0; ms < 16; ++ms) s += s_red[ms][t];
        attn_h[(size_t)id*CHN + t] = s;
    }
}

// ---------------------------------------------------------------------------
// Kernel 4: conv partial-U per (z,a,b-chunk64).
// grid = Z*NPT*NCHC = 2048 blocks, 256 threads.
// ---------------------------------------------------------------------------
__global__ __launch_bounds__(256)
void conv_partial_kernel(const float* __restrict__ xyz, const float* __restrict__ C0,
                         const float* __restrict__ C1, const float* __restrict__ attn_h,
                         float* __restrict__ Uc) {
    int id = blockIdx.x;             // (z*NPT + a)*NCHC + c
    int c  = id & (NCHC-1);
    int za = id >> 2;
    int z  = za >> 8;
    int b0 = c * CCH;
    int t  = threadIdx.x;
    int g    = t >> 7;               // b sub-half: 32 bt each
    int mloc = t & 127;

    __shared__ float s_xyz[3];
    __shared__ float s_b10[CCH][NBK];
    __shared__ float s_ao[CCH][CHN];
    __shared__ float s_h1[HD][CCH+4];
    __shared__ float s_U[HD][CHN+1];

    if (t < 3) s_xyz[t] = xyz[za*3 + t];
    for (int idx = t; idx < CCH*CHN; idx += 256) {
        int bt = idx >> 4, j = idx & 15;
        int b = b0 + bt;
        s_ao[bt][j] = attn_h[((size_t)(z*NH + 0)*NPT + b)*CHN + j]
                    + attn_h[((size_t)(z*NH + 1)*NPT + b)*CHN + j];
    }
    __syncthreads();
    if (t < CCH) {
        int b = b0 + t;
        float dx = xyz[(z*NPT+b)*3+0] - s_xyz[0];
        float dy = xyz[(z*NPT+b)*3+1] - s_xyz[1];
        float dz = xyz[(z*NPT+b)*3+2] - s_xyz[2];
        float d = sqrtf(dx*dx + dy*dy + dz*dz + 1e-12f);
        #pragma unroll
        for (int n = 0; n < NBK; ++n) {
            float diff = (d - n*(5.0f/9.0f)) * 1.8f;
            s_b10[t][n] = (fabsf(diff) < 1.0f) ? __cosf(1.57079632679f*diff) : 0.f;
        }
    }
    __syncthreads();
    if (mloc < HD) {
        int n = mloc;
        float w[NBK];
        #pragma unroll
        for (int k = 0; k < NBK; ++k) w[k] = C0[k*HD + n];
        #pragma unroll
        for (int bl = 0; bl < 32; ++bl) {
            int btg = g*32 + bl;
            float s = 0.f;
            #pragma unroll
            for (int k = 0; k < NBK; ++k) s += s_b10[btg][k] * w[k];
            s_h1[n][btg] = swishf(s);
        }
    }
    __syncthreads();
    float U[16];
    #pragma unroll
    for (int j = 0; j < 16; ++j) U[j] = 0.f;
    if (mloc < HD) {
        int m = mloc;
        float acc[32];
        #pragma unroll
        for (int i = 0; i < 32; ++i) acc[i] = 0.f;
        const float* c1 = C1 + m;                // C1[n][m]
        #pragma unroll 2
        for (int n = 0; n < HD; ++n) {
            float w = c1[n*HD];
            const float4* hp = (const float4*)&s_h1[n][g*32];
            float4 x0 = hp[0], x1 = hp[1], x2 = hp[2], x3 = hp[3];
            float4 x4 = hp[4], x5 = hp[5], x6 = hp[6], x7 = hp[7];
            acc[0]+=x0.x*w;  acc[1]+=x0.y*w;  acc[2]+=x0.z*w;  acc[3]+=x0.w*w;
            acc[4]+=x1.x*w;  acc[5]+=x1.y*w;  acc[6]+=x1.z*w;  acc[7]+=x1.w*w;
            acc[8]+=x2.x*w;  acc[9]+=x2.y*w;  acc[10]+=x2.z*w; acc[11]+=x2.w*w;
            acc[12]+=x3.x*w; acc[13]+=x3.y*w; acc[14]+=x3.z*w; acc[15]+=x3.w*w;
            acc[16]+=x4.x*w; acc[17]+=x4.y*w; acc[18]+=x4.z*w; acc[19]+=x4.w*w;
            acc[20]+=x5.x*w; acc[21]+=x5.y*w; acc[22]+=x5.z*w; acc[23]+=x5.w*w;
            acc[24]+=x6.x*w; acc[25]+=x6.y*w; acc[26]+=x6.z*w; acc[27]+=x6.w*w;
            acc[28]+=x7.x*w; acc[29]+=x7.y*w; acc[30]+=x7.z*w; acc[31]+=x7.w*w;
        }
        #pragma unroll
        for (int bl = 0; bl < 32; ++bl) {
            float t1 = swishf(acc[bl]);
            const float4* ap = (const float4*)&s_ao[g*32 + bl][0];
            float4 a0 = ap[0], a1 = ap[1], a2 = ap[2], a3 = ap[3];
            U[0]+=t1*a0.x;  U[1]+=t1*a0.y;  U[2]+=t1*a0.z;  U[3]+=t1*a0.w;
            U[4]+=t1*a1.x;  U[5]+=t1*a1.y;  U[6]+=t1*a1.z;  U[7]+=t1*a1.w;
            U[8]+=t1*a2.x;  U[9]+=t1*a2.y;  U[10]+=t1*a2.z; U[11]+=t1*a2.w;
            U[12]+=t1*a3.x; U[13]+=t1*a3.y; U[14]+=t1*a3.z; U[15]+=t1*a3.w;
        }
        if (g == 1) {
            #pragma unroll
            for (int j = 0; j < 16; ++j) s_U[m][j] = U[j];
        }
    }
    __syncthreads();
    if (g == 0 && mloc < HD) {
        int m = mloc;
        float* uc = Uc + (size_t)id*HD*CHN + m*CHN;
        #pragma unroll
        for (int j = 0; j < 16; ++j) uc[j] = s_U[m][j] + U[j];
    }
}

// ---------------------------------------------------------------------------
// Kernel 5: reduce conv partials and contract with Cf.
// grid = Z*NPT = 512 blocks, 256 threads.
// ---------------------------------------------------------------------------
__global__ __launch_bounds__(256)
void conv_reduce_kernel(const float* __restrict__ Uc, const float* __restrict__ Cf,
                        float* __restrict__ out) {
    int za = blockIdx.x;
    int t = threadIdx.x;
    __shared__ float s_U[HD*CHN];
    __shared__ float s_red[16][16];
    for (int idx = t; idx < HD*CHN; idx += 256) {
        float s = 0.f;
        #pragma unroll
        for (int c = 0; c < NCHC; ++c) s += Uc[((size_t)za*NCHC + c)*HD*CHN + idx];
        s_U[idx] = s;
    }
    __syncthreads();
    {
        int i = t & 15, ms = t >> 4;
        float acc = 0.f;
        for (int m = ms; m < HD; m += 16) {
            const float* cf = Cf + (size_t)m*256 + i*16;
            const float* Um = &s_U[m*CHN];
            #pragma unroll
            for (int j = 0; j < 16; ++j) acc += Um[j] * cf[j];
        }
        s_red[ms][i] = acc;
    }
    __syncthreads();
    if (t < 16) {
        float s = 0.f;
        #pragma unroll
        for (int ms = 0; ms < 16; ++ms) s += s_red[ms][t];
        out[za*CHN + t] = s;
    }
}

// ---------------------------------------------------------------------------
extern "C" void kernel_launch(void* const* d_in, const int* in_sizes, int n_in,
                              void* d_out, int out_size, void* d_ws, size_t ws_size,
                              hipStream_t stream) {
    const float* f   = (const float*)d_in[0];
    const float* xyz = (const float*)d_in[1];
    const float* Wq  = (const float*)d_in[2];
    const float* K0  = (const float*)d_in[3];
    const float* K1  = (const float*)d_in[4];
    const float* Kf  = (const float*)d_in[5];
    const float* V0  = (const float*)d_in[6];
    const float* Vf  = (const float*)d_in[7];
    const float* C0  = (const float*)d_in[8];
    const float* C1  = (const float*)d_in[9];
    const float* Cf  = (const float*)d_in[10];
    float* out = (float*)d_out;

    // workspace layout (floats)
    float* Gq     = (float*)d_ws;                       // Z*NH*NPT*HD*CHN = 1,638,400
    float* scores = Gq + (size_t)Z*NH*NPT*HD*CHN;       // Z*NH*NPT*NPT   =   262,144
    float* p      = scores + (size_t)Z*NH*NPT*NPT;      //                =   262,144
    float* attn_h = p + (size_t)Z*NH*NPT*NPT;           // Z*NH*NPT*CHN   =    16,384
    float* Uc     = attn_h + (size_t)Z*NH*NPT*CHN;      // Z*NPT*NCHC*HD*CHN = 3,276,800

    gq_kernel          <<<Z*NH*NPT,        256, 0, stream>>>(f, Wq, Kf, Gq);
    score_kernel       <<<Z*NH*NPT*NCHS,   256, 0, stream>>>(f, xyz, K0, K1, Gq, scores);
    softmax_kernel     <<<Z*NH*NPT,         64, 0, stream>>>(scores, p);
    attn_value_kernel  <<<Z*NH*NPT,        256, 0, stream>>>(f, xyz, V0, Vf, p, attn_h);
    conv_partial_kernel<<<Z*NPT*NCHC,      256, 0, stream>>>(xyz, C0, C1, attn_h, Uc);
    conv_reduce_kernel <<<Z*NPT,           256, 0, stream>>>(Uc, Cf, out);
}

// Round 3
// 278.554 us; speedup vs baseline: 2.6701x; 1.3808x over previous
//
#include <hip/hip_runtime.h>
#include <math.h>

// Problem constants (fixed by reference)
#define Z 2
#define NPT 256     // points per batch
#define CHN 16      // channels
#define NH 2        // heads
#define NBK 10      // key/conv radial basis
#define HD 100      // radial hidden width
#define NBV 3       // value radial basis
#define G 2048      // radial table grid points
#define DMAX (5.0f + 5.0f/9.0f)   // beyond this all cosine bases = 0 -> h2 = 0 exactly
#define CCH 64      // b-chunk in conv partial kernel
#define NCHC (NPT/CCH)   // 4

__device__ __forceinline__ float swishf(float x) {
    return x / (1.0f + __expf(-x));
}

// ---------------------------------------------------------------------------
// Kernel 0: build radial tables.
//   TK[h][g][m] = h2_key(d_g)  (2 heads),  TC[g][m] = h2_conv(d_g)
// d_g = g * DMAX/(G-1); T[G-1] = 0 exactly (all bases zero at DMAX).
// grid = G/32 = 64 blocks, 256 threads. Per block: 32 grid points.
// ---------------------------------------------------------------------------
__global__ __launch_bounds__(256)
void build_tables(const float* __restrict__ K0, const float* __restrict__ K1,
                  const float* __restrict__ C0, const float* __restrict__ C1,
                  float* __restrict__ TK, float* __restrict__ TC) {
    int gp0 = blockIdx.x * 32;
    int t = threadIdx.x;
    int mh = t & 127, half = t >> 7;
    __shared__ float s_b10[32][NBK];
    __shared__ __align__(16) float s_h1[HD*36];   // [n][gpt], row 36 floats = 144B (16B-aligned)

    if (t < 32) {
        float d = (gp0 + t) * (DMAX / (float)(G-1));
        #pragma unroll
        for (int n = 0; n < NBK; ++n) {
            float diff = (d - n*(5.0f/9.0f)) * 1.8f;
            s_b10[t][n] = (fabsf(diff) < 1.0f) ? __cosf(1.57079632679f*diff) : 0.f;
        }
    }
    __syncthreads();
    for (int rep = 0; rep < 3; ++rep) {
        const float* W0 = (rep < 2) ? (K0 + rep*NBK*HD) : C0;
        const float* W1 = (rep < 2) ? (K1 + rep*HD*HD)  : C1;
        float* outp     = (rep < 2) ? (TK + (size_t)rep*G*HD) : TC;
        if (mh < HD) {
            int n = mh;
            float w[NBK];
            #pragma unroll
            for (int q = 0; q < NBK; ++q) w[q] = W0[q*HD + n];
            #pragma unroll
            for (int k = 0; k < 16; ++k) {
                int gpt = half*16 + k;
                float s = 0.f;
                #pragma unroll
                for (int q = 0; q < NBK; ++q) s += s_b10[gpt][q] * w[q];
                s_h1[n*36 + gpt] = swishf(s);
            }
        }
        __syncthreads();
        if (mh < HD) {
            int m = mh;
            float acc[16];
            #pragma unroll
            for (int k = 0; k < 16; ++k) acc[k] = 0.f;
            const float* w1 = W1 + m;
            for (int n = 0; n < HD; ++n) {
                float w = w1[n*HD];
                const float4* hp = (const float4*)&s_h1[n*36 + half*16];
                float4 x0 = hp[0], x1 = hp[1], x2 = hp[2], x3 = hp[3];
                acc[0]+=x0.x*w;  acc[1]+=x0.y*w;  acc[2]+=x0.z*w;  acc[3]+=x0.w*w;
                acc[4]+=x1.x*w;  acc[5]+=x1.y*w;  acc[6]+=x1.z*w;  acc[7]+=x1.w*w;
                acc[8]+=x2.x*w;  acc[9]+=x2.y*w;  acc[10]+=x2.z*w; acc[11]+=x2.w*w;
                acc[12]+=x3.x*w; acc[13]+=x3.y*w; acc[14]+=x3.z*w; acc[15]+=x3.w*w;
            }
            #pragma unroll
            for (int k = 0; k < 16; ++k)
                outp[(size_t)(gp0 + half*16 + k)*HD + m] = swishf(acc[k]);
        }
        __syncthreads();
    }
}

// ---------------------------------------------------------------------------
// Kernel 1: fused q/Gq + scores (table lerp) + softmax + value-U + Vf epilogue.
// One block per (z,h,a) = 1024 blocks, 256 threads (4 waves).
// ---------------------------------------------------------------------------
__global__ __launch_bounds__(256)
void fused_attn(const float* __restrict__ f, const float* __restrict__ xyz,
                const float* __restrict__ Wq, const float* __restrict__ Kf,
                const float* __restrict__ V0, const float* __restrict__ Vf,
                const float* __restrict__ TK, float* __restrict__ attn_h) {
    int id = blockIdx.x;            // (z*NH + h)*NPT + a
    int a  = id & 255;
    int zh = id >> 8;
    int h  = zh & 1;
    int z  = zh >> 1;
    int t  = threadIdx.x;
    int mh = t & 127, half = t >> 7;

    __shared__ __align__(16) float s_f[NPT*CHN];   // 16 KB, f[z] staged whole
    __shared__ float s_q[CHN];
    __shared__ __align__(16) float s_gq[HD*20];    // 8 KB, [m][j] padded to 20
    __shared__ float s_b3[NPT][NBV];               // 3 KB value basis
    __shared__ int   s_gi[NPT];                    // 1 KB table index per b
    __shared__ float s_fr[NPT];                    // 1 KB lerp frac per b
    __shared__ float s_sc[NPT];                    // scores, then p (in-place)
    __shared__ float s_ps[32*104];                 // 13.3 KB score partials [bl][m]
    __shared__ float s_red[8];
    __shared__ __align__(16) float s_U[HD*20];     // 8 KB U[m][j] padded to 20
    __shared__ float s_red2[16][16];

    // --- phase 1: stage features, distances/bases/table-coords, q, Gq ---
    {
        const float4* fz = (const float4*)(f + (size_t)z*NPT*CHN);
        float4* sf = (float4*)s_f;
        for (int i = t; i < NPT*CHN/4; i += 256) sf[i] = fz[i];
    }
    {
        float ax = xyz[(z*NPT + a)*3 + 0];
        float ay = xyz[(z*NPT + a)*3 + 1];
        float az = xyz[(z*NPT + a)*3 + 2];
        int b = t;
        float dx = xyz[(z*NPT + b)*3 + 0] - ax;
        float dy = xyz[(z*NPT + b)*3 + 1] - ay;
        float dz = xyz[(z*NPT + b)*3 + 2] - az;
        float d = sqrtf(dx*dx + dy*dy + dz*dz + 1e-12f);
        float fd = d * ((float)(G-1) / DMAX);
        int   gi = (int)fd;
        float fr = fd - (float)gi;
        if (gi >= G-1) { gi = G-2; fr = 1.0f; }   // d beyond support -> T[G-1] = 0
        s_gi[b] = gi; s_fr[b] = fr;
        #pragma unroll
        for (int n = 0; n < NBV; ++n) {
            float diff = (d - n*2.5f) * 0.4f;
            s_b3[b][n] = (fabsf(diff) < 1.0f) ? __cosf(1.57079632679f*diff) : 0.f;
        }
    }
    __syncthreads();
    if (t < CHN) {
        float s = 0.f;
        const float* wq = Wq + (h*CHN + t)*CHN;   // Wq[h][o][i]
        #pragma unroll
        for (int i = 0; i < CHN; ++i) s += s_f[a*CHN + i] * wq[i];
        s_q[t] = s;
    }
    __syncthreads();
    {   // Gq[m][j] = sum_i Kf[h][m][i*16+j] * q[i]
        const float* kf = Kf + (size_t)h*HD*256;
        for (int idx = t; idx < HD*CHN; idx += 256) {
            int m = idx >> 4, j = idx & 15;
            float s = 0.f;
            #pragma unroll
            for (int i = 0; i < CHN; ++i) s += kf[m*256 + i*16 + j] * s_q[i];
            s_gq[m*20 + j] = s;
        }
    }
    __syncthreads();

    // --- phase 2: scores via table lerp; gq row hoisted into registers ---
    float gq[16];
    if (mh < HD) {
        const float4* gp = (const float4*)&s_gq[mh*20];
        float4 g0 = gp[0], g1 = gp[1], g2 = gp[2], g3 = gp[3];
        gq[0]=g0.x;  gq[1]=g0.y;  gq[2]=g0.z;  gq[3]=g0.w;
        gq[4]=g1.x;  gq[5]=g1.y;  gq[6]=g1.z;  gq[7]=g1.w;
        gq[8]=g2.x;  gq[9]=g2.y;  gq[10]=g2.z; gq[11]=g2.w;
        gq[12]=g3.x; gq[13]=g3.y; gq[14]=g3.z; gq[15]=g3.w;
    }
    const float* tkh = TK + (size_t)h*G*HD;
    for (int r = 0; r < 8; ++r) {
        if (mh < HD) {
            #pragma unroll 2
            for (int k = 0; k < 16; ++k) {
                int bl = half*16 + k;
                int b  = r*32 + bl;
                int gi = s_gi[b];
                float fr = s_fr[b];
                float t0 = tkh[(size_t)gi*HD + mh];       // coalesced across m-lanes
                float t1 = tkh[(size_t)(gi+1)*HD + mh];
                float h2 = t0 + fr*(t1 - t0);
                const float4* fp = (const float4*)&s_f[b*CHN];  // broadcast
                float4 f0 = fp[0], f1 = fp[1], f2 = fp[2], f3 = fp[3];
                float gf = gq[0]*f0.x + gq[1]*f0.y + gq[2]*f0.z + gq[3]*f0.w
                         + gq[4]*f1.x + gq[5]*f1.y + gq[6]*f1.z + gq[7]*f1.w
                         + gq[8]*f2.x + gq[9]*f2.y + gq[10]*f2.z + gq[11]*f2.w
                         + gq[12]*f3.x + gq[13]*f3.y + gq[14]*f3.z + gq[15]*f3.w;
                s_ps[bl*104 + mh] = h2 * gf;
            }
        }
        __syncthreads();
        {
            int b = t >> 3, s8 = t & 7;
            float s = 0.f;
            for (int m = s8; m < HD; m += 8) s += s_ps[b*104 + m];
            s += __shfl_down(s, 4, 8);
            s += __shfl_down(s, 2, 8);
            s += __shfl_down(s, 1, 8);
            if (s8 == 0) s_sc[r*32 + b] = s * (1.0f/16.0f);
        }
        __syncthreads();
    }

    // --- phase 3: softmax over 256 scores (in-block) ---
    {
        float v = s_sc[t];
        float mx = v;
        #pragma unroll
        for (int off = 32; off >= 1; off >>= 1) mx = fmaxf(mx, __shfl_xor(mx, off));
        int wid = t >> 6;
        if ((t & 63) == 0) s_red[wid] = mx;
        __syncthreads();
        mx = fmaxf(fmaxf(s_red[0], s_red[1]), fmaxf(s_red[2], s_red[3]));
        float e = __expf(v - mx);
        float sm = e;
        #pragma unroll
        for (int off = 32; off >= 1; off >>= 1) sm += __shfl_xor(sm, off);
        if ((t & 63) == 0) s_red[4 + wid] = sm;
        __syncthreads();
        float tot = s_red[4] + s_red[5] + s_red[6] + s_red[7];
        s_sc[t] = e / tot;          // overwrite scores with p
    }
    __syncthreads();

    // --- phase 4: U[m,j] = sum_b p_b * h1v(d_b)[m] * f[b,j] ---
    float U[16];
    #pragma unroll
    for (int j2 = 0; j2 < 16; ++j2) U[j2] = 0.f;
    if (mh < HD) {
        float w0 = V0[(h*NBV + 0)*HD + mh];
        float w1 = V0[(h*NBV + 1)*HD + mh];
        float w2 = V0[(h*NBV + 2)*HD + mh];
        int b0 = half * 128;
        for (int bb = 0; bb < 128; ++bb) {
            int b = b0 + bb;
            float hv = swishf(s_b3[b][0]*w0 + s_b3[b][1]*w1 + s_b3[b][2]*w2);
            float t1 = s_sc[b] * hv;
            const float4* fp = (const float4*)&s_f[b*CHN];
            float4 f0 = fp[0], f1 = fp[1], f2 = fp[2], f3 = fp[3];
            U[0]+=t1*f0.x;  U[1]+=t1*f0.y;  U[2]+=t1*f0.z;  U[3]+=t1*f0.w;
            U[4]+=t1*f1.x;  U[5]+=t1*f1.y;  U[6]+=t1*f1.z;  U[7]+=t1*f1.w;
            U[8]+=t1*f2.x;  U[9]+=t1*f2.y;  U[10]+=t1*f2.z; U[11]+=t1*f2.w;
            U[12]+=t1*f3.x; U[13]+=t1*f3.y; U[14]+=t1*f3.z; U[15]+=t1*f3.w;
        }
    }
    if (half == 1 && mh < HD) {
        #pragma unroll
        for (int j2 = 0; j2 < 16; ++j2) s_U[mh*20 + j2] = U[j2];
    }
    __syncthreads();
    if (half == 0 && mh < HD) {
        #pragma unroll
        for (int j2 = 0; j2 < 16; ++j2) s_U[mh*20 + j2] += U[j2];
    }
    __syncthreads();
    // --- epilogue: attn_h[id][i] = sum_{m,j} U[m,j] * Vf[h][m][i*16+j] ---
    {
        int i = t & 15, ms = t >> 4;
        float acc = 0.f;
        for (int m = ms; m < HD; m += 16) {
            const float* vf = Vf + ((size_t)h*HD + m)*256 + i*16;
            const float* Um = &s_U[m*20];
            #pragma unroll
            for (int j2 = 0; j2 < 16; ++j2) acc += Um[j2] * vf[j2];
        }
        s_red2[ms][i] = acc;
    }
    __syncthreads();
    if (t < 16) {
        float s = 0.f;
        #pragma unroll
        for (int ms = 0; ms < 16; ++ms) s += s_red2[ms][t];
        attn_h[(size_t)id*CHN + t] = s;
    }
}

// ---------------------------------------------------------------------------
// Kernel 2: conv partial-U per (z,a,b-chunk64) using TC table lerp.
// grid = Z*NPT*NCHC = 2048 blocks, 256 threads.
// ---------------------------------------------------------------------------
__global__ __launch_bounds__(256)
void conv_partial_kernel(const float* __restrict__ xyz, const float* __restrict__ TC,
                         const float* __restrict__ attn_h, float* __restrict__ Uc) {
    int id = blockIdx.x;             // (z*NPT + a)*NCHC + c
    int c  = id & (NCHC-1);
    int za = id >> 2;
    int z  = za >> 8;
    int b0 = c * CCH;
    int t  = threadIdx.x;
    int mh = t & 127, half = t >> 7;

    __shared__ __align__(16) float s_ao[CCH][CHN];
    __shared__ int   s_gi[CCH];
    __shared__ float s_fr[CCH];
    __shared__ float s_U[HD*20];

    for (int idx = t; idx < CCH*CHN; idx += 256) {
        int bt = idx >> 4, j = idx & 15;
        int b = b0 + bt;
        s_ao[bt][j] = attn_h[((size_t)(z*NH + 0)*NPT + b)*CHN + j]
                    + attn_h[((size_t)(z*NH + 1)*NPT + b)*CHN + j];
    }
    if (t < CCH) {
        int b = b0 + t;
        float dx = xyz[(z*NPT+b)*3+0] - xyz[za*3+0];
        float dy = xyz[(z*NPT+b)*3+1] - xyz[za*3+1];
        float dz = xyz[(z*NPT+b)*3+2] - xyz[za*3+2];
        float d = sqrtf(dx*dx + dy*dy + dz*dz + 1e-12f);
        float fd = d * ((float)(G-1) / DMAX);
        int   gi = (int)fd;
        float fr = fd - (float)gi;
        if (gi >= G-1) { gi = G-2; fr = 1.0f; }
        s_gi[t] = gi; s_fr[t] = fr;
    }
    __syncthreads();
    float U[16];
    #pragma unroll
    for (int j2 = 0; j2 < 16; ++j2) U[j2] = 0.f;
    if (mh < HD) {
        #pragma unroll 2
        for (int bb = 0; bb < 32; ++bb) {
            int bl = half*32 + bb;
            int gi = s_gi[bl];
            float fr = s_fr[bl];
            float t0 = TC[(size_t)gi*HD + mh];
            float t1 = TC[(size_t)(gi+1)*HD + mh];
            float h2 = t0 + fr*(t1 - t0);
            const float4* ap = (const float4*)&s_ao[bl][0];
            float4 a0 = ap[0], a1 = ap[1], a2 = ap[2], a3 = ap[3];
            U[0]+=h2*a0.x;  U[1]+=h2*a0.y;  U[2]+=h2*a0.z;  U[3]+=h2*a0.w;
            U[4]+=h2*a1.x;  U[5]+=h2*a1.y;  U[6]+=h2*a1.z;  U[7]+=h2*a1.w;
            U[8]+=h2*a2.x;  U[9]+=h2*a2.y;  U[10]+=h2*a2.z; U[11]+=h2*a2.w;
            U[12]+=h2*a3.x; U[13]+=h2*a3.y; U[14]+=h2*a3.z; U[15]+=h2*a3.w;
        }
        if (half == 1) {
            #pragma unroll
            for (int j2 = 0; j2 < 16; ++j2) s_U[mh*20 + j2] = U[j2];
        }
    }
    __syncthreads();
    if (half == 0 && mh < HD) {
        int m = mh;
        float* uc = Uc + (size_t)id*HD*CHN + m*CHN;
        #pragma unroll
        for (int j2 = 0; j2 < 16; ++j2) uc[j2] = s_U[m*20 + j2] + U[j2];
    }
}

// ---------------------------------------------------------------------------
// Kernel 3: reduce conv partials and contract with Cf.
// grid = Z*NPT = 512 blocks, 256 threads.
// ---------------------------------------------------------------------------
__global__ __launch_bounds__(256)
void conv_reduce_kernel(const float* __restrict__ Uc, const float* __restrict__ Cf,
                        float* __restrict__ out) {
    int za = blockIdx.x;
    int t = threadIdx.x;
    __shared__ float s_U[HD*CHN];
    __shared__ float s_red[16][16];
    for (int idx = t; idx < HD*CHN; idx += 256) {
        float s = 0.f;
        #pragma unroll
        for (int c = 0; c < NCHC; ++c) s += Uc[((size_t)za*NCHC + c)*HD*CHN + idx];
        s_U[idx] = s;
    }
    __syncthreads();
    {
        int i = t & 15, ms = t >> 4;
        float acc = 0.f;
        for (int m = ms; m < HD; m += 16) {
            const float* cf = Cf + (size_t)m*256 + i*16;
            const float* Um = &s_U[m*CHN];
            #pragma unroll
            for (int j = 0; j < 16; ++j) acc += Um[j] * cf[j];
        }
        s_red[ms][i] = acc;
    }
    __syncthreads();
    if (t < 16) {
        float s = 0.f;
        #pragma unroll
        for (int ms = 0; ms < 16; ++ms) s += s_red[ms][t];
        out[za*CHN + t] = s;
    }
}

// ---------------------------------------------------------------------------
extern "C" void kernel_launch(void* const* d_in, const int* in_sizes, int n_in,
                              void* d_out, int out_size, void* d_ws, size_t ws_size,
                              hipStream_t stream) {
    const float* f   = (const float*)d_in[0];
    const float* xyz = (const float*)d_in[1];
    const float* Wq  = (const float*)d_in[2];
    const float* K0  = (const float*)d_in[3];
    const float* K1  = (const float*)d_in[4];
    const float* Kf  = (const float*)d_in[5];
    const float* V0  = (const float*)d_in[6];
    const float* Vf  = (const float*)d_in[7];
    const float* C0  = (const float*)d_in[8];
    const float* C1  = (const float*)d_in[9];
    const float* Cf  = (const float*)d_in[10];
    float* out = (float*)d_out;

    // workspace layout (floats): TK 409600 | TC 204800 | attn_h 16384 | Uc 3276800
    float* TK     = (float*)d_ws;
    float* TC     = TK + (size_t)NH*G*HD;
    float* attn_h = TC + (size_t)G*HD;
    float* Uc     = attn_h + (size_t)Z*NH*NPT*CHN;

    build_tables       <<<G/32,       256, 0, stream>>>(K0, K1, C0, C1, TK, TC);
    fused_attn         <<<Z*NH*NPT,   256, 0, stream>>>(f, xyz, Wq, Kf, V0, Vf, TK, attn_h);
    conv_partial_kernel<<<Z*NPT*NCHC, 256, 0, stream>>>(xyz, TC, attn_h, Uc);
    conv_reduce_kernel <<<Z*NPT,      256, 0, stream>>>(Uc, Cf, out);
}

// Round 5
// 194.102 us; speedup vs baseline: 3.8318x; 1.4351x over previous
//
#include <hip/hip_runtime.h>
#include <math.h>

// Problem constants (fixed by reference)
#define Z 2
#define NPT 256     // points per batch
#define CHN 16      // channels
#define NH 2        // heads
#define NBK 10      // key/conv radial basis
#define HD 100      // radial hidden width
#define NBV 3       // value radial basis
#define G 2048      // radial table grid points
#define DMAX (5.0f + 5.0f/9.0f)   // beyond this all cosine bases = 0 -> h2 = 0 exactly

__device__ __forceinline__ float swishf(float x) {
    return x / (1.0f + __expf(-x));
}

// ---------------------------------------------------------------------------
// Kernel 1: build radial tables as interleaved float2 {T[g], T[g+1]}.
// 3 reps (key h0, key h1, conv) x 2048 grid pts; 16 pts per block.
// grid = 384 blocks x 128 threads. rep = bid/128, g0 = (bid%128)*16.
// ---------------------------------------------------------------------------
__global__ __launch_bounds__(128)
void build_tables(const float* __restrict__ K0, const float* __restrict__ K1,
                  const float* __restrict__ C0, const float* __restrict__ C1,
                  float* __restrict__ TKf, float* __restrict__ TCf) {
    int bid = blockIdx.x;
    int rep = bid >> 7;              // 0,1: key heads; 2: conv
    int g0  = (bid & 127) * 16;
    int t   = threadIdx.x;
    const float* W0 = (rep == 0) ? K0 : (rep == 1) ? (K0 + NBK*HD) : C0;
    const float* W1 = (rep == 0) ? K1 : (rep == 1) ? (K1 + HD*HD)  : C1;
    float* Tf       = (rep == 0) ? TKf : (rep == 1) ? (TKf + 2*(size_t)G*HD) : TCf;

    __shared__ float s_b10[16][NBK];
    __shared__ __align__(16) float s_h1[HD*16];   // [n][k]

    if (t < 16) {
        float d = (g0 + t) * (DMAX / (float)(G-1));
        #pragma unroll
        for (int q = 0; q < NBK; ++q) {
            float diff = (d - q*(5.0f/9.0f)) * 1.8f;
            s_b10[t][q] = (fabsf(diff) < 1.0f) ? __cosf(1.57079632679f*diff) : 0.f;
        }
    }
    __syncthreads();
    if (t < HD) {
        int n = t;
        float w[NBK];
        #pragma unroll
        for (int q = 0; q < NBK; ++q) w[q] = W0[q*HD + n];
        #pragma unroll
        for (int k = 0; k < 16; ++k) {
            float s = 0.f;
            #pragma unroll
            for (int q = 0; q < NBK; ++q) s += s_b10[k][q] * w[q];
            s_h1[n*16 + k] = swishf(s);
        }
    }
    __syncthreads();
    if (t < HD) {
        int m = t;
        float acc[16];
        #pragma unroll
        for (int k = 0; k < 16; ++k) acc[k] = 0.f;
        const float* w1 = W1 + m;
        #pragma unroll 2
        for (int n = 0; n < HD; ++n) {
            float w = w1[n*HD];                           // coalesced across m
            const float4* hp = (const float4*)&s_h1[n*16]; // broadcast
            float4 x0 = hp[0], x1 = hp[1], x2 = hp[2], x3 = hp[3];
            acc[0]+=x0.x*w;  acc[1]+=x0.y*w;  acc[2]+=x0.z*w;  acc[3]+=x0.w*w;
            acc[4]+=x1.x*w;  acc[5]+=x1.y*w;  acc[6]+=x1.z*w;  acc[7]+=x1.w*w;
            acc[8]+=x2.x*w;  acc[9]+=x2.y*w;  acc[10]+=x2.z*w; acc[11]+=x2.w*w;
            acc[12]+=x3.x*w; acc[13]+=x3.y*w; acc[14]+=x3.z*w; acc[15]+=x3.w*w;
        }
        #pragma unroll
        for (int k = 0; k < 16; ++k) {
            float v = swishf(acc[k]);
            int gg = g0 + k;
            Tf[2*((size_t)gg*HD + m) + 0] = v;                  // .x of row gg
            if (gg > 0) Tf[2*((size_t)(gg-1)*HD + m) + 1] = v;  // .y of row gg-1
        }
    }
}

// ---------------------------------------------------------------------------
// Kernel 2: fused q/Gq + scores (wave-shuffle m-reduction, table lerp) +
// softmax + value-U + Vf epilogue. One block per (z,h,a) = 1024 blocks.
// LDS 31.6 KB -> 5 blocks/CU capacity; VGPR capped at 128 via bounds.
// ---------------------------------------------------------------------------
__global__ __launch_bounds__(256, 4)
void fused_attn(const float* __restrict__ f, const float* __restrict__ xyz,
                const float* __restrict__ Wq, const float* __restrict__ Kf,
                const float* __restrict__ V0, const float* __restrict__ Vf,
                const float2* __restrict__ TK2, float* __restrict__ attn_h) {
    int bid = blockIdx.x;            // (z*NH + h)*NPT + a
    int a  = bid & 255;
    int zh = bid >> 8;
    int h  = zh & 1;
    int z  = zh >> 1;
    int t  = threadIdx.x;

    __shared__ __align__(16) float s_f[NPT*CHN];   // 16384 B
    __shared__ __align__(16) float s_gu[HD*20];    // 8000 B  gq then U
    __shared__ float s_b3[NPT*NBV];                // 3072 B
    __shared__ int   s_gi[NPT];                    // 1024 B
    __shared__ float s_fr[NPT];                    // 1024 B
    __shared__ float s_sc[NPT];                    // 1024 B  scores then p
    __shared__ float s_red[8];
    __shared__ float s_red2[256];                  // q early; Vf partials late

    // phase 1: stage features, per-b geometry, q, gq
    {
        const float4* fz = (const float4*)(f + (size_t)z*NPT*CHN);
        float4* sf = (float4*)s_f;
        for (int i = t; i < NPT*CHN/4; i += 256) sf[i] = fz[i];
    }
    {
        float ax = xyz[(z*NPT + a)*3 + 0];
        float ay = xyz[(z*NPT + a)*3 + 1];
        float az = xyz[(z*NPT + a)*3 + 2];
        int b = t;
        float dx = xyz[(z*NPT + b)*3 + 0] - ax;
        float dy = xyz[(z*NPT + b)*3 + 1] - ay;
        float dz = xyz[(z*NPT + b)*3 + 2] - az;
        float d = sqrtf(dx*dx + dy*dy + dz*dz + 1e-12f);
        float fd = d * ((float)(G-1) / DMAX);
        int   gi = (int)fd;
        float fr = fd - (float)gi;
        if (gi >= G-1) { gi = G-2; fr = 1.0f; }    // beyond support -> exact 0
        s_gi[b] = gi; s_fr[b] = fr;
        #pragma unroll
        for (int n = 0; n < NBV; ++n) {
            float diff = (d - n*2.5f) * 0.4f;
            s_b3[b*NBV + n] = (fabsf(diff) < 1.0f) ? __cosf(1.57079632679f*diff) : 0.f;
        }
    }
    __syncthreads();
    if (t < CHN) {       // q[o] = sum_i f[a,i] * Wq[h][o][i]
        float s = 0.f;
        const float* wq = Wq + (h*CHN + t)*CHN;
        #pragma unroll
        for (int i = 0; i < CHN; ++i) s += s_f[a*CHN + i] * wq[i];
        s_red2[t] = s;
    }
    __syncthreads();
    {   // gq[m][j] = sum_i Kf[h][m][i*16+j] * q[i]
        const float* kf = Kf + (size_t)h*HD*256;
        for (int idx = t; idx < HD*CHN; idx += 256) {
            int m = idx >> 4, j = idx & 15;
            float s = 0.f;
            #pragma unroll
            for (int i = 0; i < CHN; ++i) s += kf[m*256 + i*16 + j] * s_red2[i];
            s_gu[m*20 + j] = s;
        }
    }
    __syncthreads();

    // phase 2: scores. wave w owns b in [w*64, w*64+64); lane covers m, m+64.
    {
        int lane = t & 63, w = t >> 6;
        int m2 = lane + 64;
        bool hasm2 = (m2 < HD);
        float gq1[16], gq2[16];
        {
            const float4* gp = (const float4*)&s_gu[lane*20];
            float4 g0 = gp[0], g1 = gp[1], g2 = gp[2], g3 = gp[3];
            gq1[0]=g0.x;  gq1[1]=g0.y;  gq1[2]=g0.z;  gq1[3]=g0.w;
            gq1[4]=g1.x;  gq1[5]=g1.y;  gq1[6]=g1.z;  gq1[7]=g1.w;
            gq1[8]=g2.x;  gq1[9]=g2.y;  gq1[10]=g2.z; gq1[11]=g2.w;
            gq1[12]=g3.x; gq1[13]=g3.y; gq1[14]=g3.z; gq1[15]=g3.w;
        }
        #pragma unroll
        for (int j = 0; j < 16; ++j) gq2[j] = 0.f;
        if (hasm2) {
            const float4* gp = (const float4*)&s_gu[m2*20];
            float4 g0 = gp[0], g1 = gp[1], g2 = gp[2], g3 = gp[3];
            gq2[0]=g0.x;  gq2[1]=g0.y;  gq2[2]=g0.z;  gq2[3]=g0.w;
            gq2[4]=g1.x;  gq2[5]=g1.y;  gq2[6]=g1.z;  gq2[7]=g1.w;
            gq2[8]=g2.x;  gq2[9]=g2.y;  gq2[10]=g2.z; gq2[11]=g2.w;
            gq2[12]=g3.x; gq2[13]=g3.y; gq2[14]=g3.z; gq2[15]=g3.w;
        }
        const float2* tk = TK2 + (size_t)h*G*HD;
        #pragma unroll 2
        for (int bb = 0; bb < 64; ++bb) {
            int b  = w*64 + bb;
            int gi = s_gi[b];
            float fr = s_fr[b];
            float2 ta = tk[(size_t)gi*HD + lane];         // coalesced
            float2 tb = make_float2(0.f, 0.f);
            if (hasm2) tb = tk[(size_t)gi*HD + m2];
            float h2a = ta.x + fr*(ta.y - ta.x);
            float h2b = tb.x + fr*(tb.y - tb.x);
            const float4* fp = (const float4*)&s_f[b*CHN];  // broadcast
            float4 f0 = fp[0], f1 = fp[1], f2 = fp[2], f3 = fp[3];
            float gfa = gq1[0]*f0.x + gq1[1]*f0.y + gq1[2]*f0.z + gq1[3]*f0.w
                      + gq1[4]*f1.x + gq1[5]*f1.y + gq1[6]*f1.z + gq1[7]*f1.w
                      + gq1[8]*f2.x + gq1[9]*f2.y + gq1[10]*f2.z + gq1[11]*f2.w
                      + gq1[12]*f3.x + gq1[13]*f3.y + gq1[14]*f3.z + gq1[15]*f3.w;
            float gfb = gq2[0]*f0.x + gq2[1]*f0.y + gq2[2]*f0.z + gq2[3]*f0.w
                      + gq2[4]*f1.x + gq2[5]*f1.y + gq2[6]*f1.z + gq2[7]*f1.w
                      + gq2[8]*f2.x + gq2[9]*f2.y + gq2[10]*f2.z + gq2[11]*f2.w
                      + gq2[12]*f3.x + gq2[13]*f3.y + gq2[14]*f3.z + gq2[15]*f3.w;
            float pp = h2a*gfa + h2b*gfb;
            pp += __shfl_xor(pp, 32);
            pp += __shfl_xor(pp, 16);
            pp += __shfl_xor(pp, 8);
            pp += __shfl_xor(pp, 4);
            pp += __shfl_xor(pp, 2);
            pp += __shfl_xor(pp, 1);
            if (lane == 0) s_sc[b] = pp * (1.0f/16.0f);
        }
    }
    __syncthreads();

    // phase 3: softmax over 256 scores
    {
        float v = s_sc[t];
        float mx = v;
        #pragma unroll
        for (int off = 32; off >= 1; off >>= 1) mx = fmaxf(mx, __shfl_xor(mx, off));
        int wid = t >> 6;
        if ((t & 63) == 0) s_red[wid] = mx;
        __syncthreads();
        mx = fmaxf(fmaxf(s_red[0], s_red[1]), fmaxf(s_red[2], s_red[3]));
        float e = __expf(v - mx);
        float s = e;
        #pragma unroll
        for (int off = 32; off >= 1; off >>= 1) s += __shfl_xor(s, off);
        if ((t & 63) == 0) s_red[4 + wid] = s;
        __syncthreads();
        float tot = s_red[4] + s_red[5] + s_red[6] + s_red[7];
        s_sc[t] = e / tot;
    }
    __syncthreads();

    // phase 4: U[m,j] = sum_b p_b * h1v(d_b)[m] * f[b,j]  (reuse s_gu)
    {
        int mh = t & 127, half = t >> 7;
        float U[16];
        #pragma unroll
        for (int j = 0; j < 16; ++j) U[j] = 0.f;
        if (mh < HD) {
            float w0 = V0[(h*NBV + 0)*HD + mh];
            float w1 = V0[(h*NBV + 1)*HD + mh];
            float w2 = V0[(h*NBV + 2)*HD + mh];
            #pragma unroll 2
            for (int bb = 0; bb < 128; ++bb) {
                int b = half*128 + bb;
                float hv = swishf(s_b3[b*NBV]*w0 + s_b3[b*NBV+1]*w1 + s_b3[b*NBV+2]*w2);
                float t1 = s_sc[b] * hv;
                const float4* fp = (const float4*)&s_f[b*CHN];
                float4 f0 = fp[0], f1 = fp[1], f2 = fp[2], f3 = fp[3];
                U[0]+=t1*f0.x;  U[1]+=t1*f0.y;  U[2]+=t1*f0.z;  U[3]+=t1*f0.w;
                U[4]+=t1*f1.x;  U[5]+=t1*f1.y;  U[6]+=t1*f1.z;  U[7]+=t1*f1.w;
                U[8]+=t1*f2.x;  U[9]+=t1*f2.y;  U[10]+=t1*f2.z; U[11]+=t1*f2.w;
                U[12]+=t1*f3.x; U[13]+=t1*f3.y; U[14]+=t1*f3.z; U[15]+=t1*f3.w;
            }
        }
        if (half == 1 && mh < HD) {
            #pragma unroll
            for (int j = 0; j < 16; ++j) s_gu[mh*20 + j] = U[j];
        }
        __syncthreads();
        if (half == 0 && mh < HD) {
            #pragma unroll
            for (int j = 0; j < 16; ++j) s_gu[mh*20 + j] += U[j];
        }
    }
    __syncthreads();
    {   // epilogue: attn_h[bid][i] = sum_{m,j} U[m,j] * Vf[h][m][i*16+j]
        int i = t & 15, ms = t >> 4;
        float acc = 0.f;
        for (int m = ms; m < HD; m += 16) {
            const float* vf = Vf + ((size_t)h*HD + m)*256 + i*16;
            const float* Um = &s_gu[m*20];
            #pragma unroll
            for (int j = 0; j < 16; ++j) acc += Um[j] * vf[j];
        }
        s_red2[ms*16 + i] = acc;
    }
    __syncthreads();
    if (t < 16) {
        float s = 0.f;
        #pragma unroll
        for (int ms = 0; ms < 16; ++ms) s += s_red2[ms*16 + t];
        attn_h[(size_t)bid*CHN + t] = s;
    }
}

// ---------------------------------------------------------------------------
// Kernel 3: final conv, one block per (z,a) = 512 blocks, 256 threads.
// Full 256-b accumulation in one block; direct store (no atomics/memset).
// ---------------------------------------------------------------------------
__global__ __launch_bounds__(256)
void conv_kernel(const float* __restrict__ xyz, const float2* __restrict__ TC2,
                 const float* __restrict__ Cf, const float* __restrict__ attn_h,
                 float* __restrict__ out) {
    int za = blockIdx.x;
    int z  = za >> 8;
    int t  = threadIdx.x;

    __shared__ __align__(16) float s_ao[NPT*CHN];  // 16384 B head-summed attn
    __shared__ float s_U[HD*20];                   // 8000 B
    __shared__ int   s_gi[NPT];
    __shared__ float s_fr[NPT];
    __shared__ float s_red2[256];

    for (int idx = t; idx < NPT*CHN; idx += 256) {
        s_ao[idx] = attn_h[(size_t)(z*NH + 0)*NPT*CHN + idx]
                  + attn_h[(size_t)(z*NH + 1)*NPT*CHN + idx];
    }
    {
        int b = t;
        float dx = xyz[(z*NPT+b)*3+0] - xyz[za*3+0];
        float dy = xyz[(z*NPT+b)*3+1] - xyz[za*3+1];
        float dz = xyz[(z*NPT+b)*3+2] - xyz[za*3+2];
        float d = sqrtf(dx*dx + dy*dy + dz*dz + 1e-12f);
        float fd = d * ((float)(G-1) / DMAX);
        int   gi = (int)fd;
        float fr = fd - (float)gi;
        if (gi >= G-1) { gi = G-2; fr = 1.0f; }
        s_gi[b] = gi; s_fr[b] = fr;
    }
    __syncthreads();
    int mh = t & 127, half = t >> 7;
    float U[16];
    #pragma unroll
    for (int j = 0; j < 16; ++j) U[j] = 0.f;
    if (mh < HD) {
        #pragma unroll 2
        for (int bb = 0; bb < 128; ++bb) {
            int b = half*128 + bb;
            int gi = s_gi[b];
            float fr = s_fr[b];
            float2 tt = TC2[(size_t)gi*HD + mh];
            float h2 = tt.x + fr*(tt.y - tt.x);
            const float4* ap = (const float4*)&s_ao[b*CHN];
            float4 a0 = ap[0], a1 = ap[1], a2 = ap[2], a3 = ap[3];
            U[0]+=h2*a0.x;  U[1]+=h2*a0.y;  U[2]+=h2*a0.z;  U[3]+=h2*a0.w;
            U[4]+=h2*a1.x;  U[5]+=h2*a1.y;  U[6]+=h2*a1.z;  U[7]+=h2*a1.w;
            U[8]+=h2*a2.x;  U[9]+=h2*a2.y;  U[10]+=h2*a2.z; U[11]+=h2*a2.w;
            U[12]+=h2*a3.x; U[13]+=h2*a3.y; U[14]+=h2*a3.z; U[15]+=h2*a3.w;
        }
    }
    if (half == 1 && mh < HD) {
        #pragma unroll
        for (int j = 0; j < 16; ++j) s_U[mh*20 + j] = U[j];
    }
    __syncthreads();
    if (half == 0 && mh < HD) {
        #pragma unroll
        for (int j = 0; j < 16; ++j) s_U[mh*20 + j] += U[j];
    }
    __syncthreads();
    {
        int i = t & 15, ms = t >> 4;
        float acc = 0.f;
        for (int m = ms; m < HD; m += 16) {
            const float* cf = Cf + (size_t)m*256 + i*16;
            const float* Um = &s_U[m*20];
            #pragma unroll
            for (int j = 0; j < 16; ++j) acc += Um[j] * cf[j];
        }
        s_red2[ms*16 + i] = acc;
    }
    __syncthreads();
    if (t < 16) {
        float s = 0.f;
        #pragma unroll
        for (int ms = 0; ms < 16; ++ms) s += s_red2[ms*16 + t];
        out[(size_t)za*CHN + t] = s;
    }
}

// ---------------------------------------------------------------------------
extern "C" void kernel_launch(void* const* d_in, const int* in_sizes, int n_in,
                              void* d_out, int out_size, void* d_ws, size_t ws_size,
                              hipStream_t stream) {
    const float* f   = (const float*)d_in[0];
    const float* xyz = (const float*)d_in[1];
    const float* Wq  = (const float*)d_in[2];
    const float* K0  = (const float*)d_in[3];
    const float* K1  = (const float*)d_in[4];
    const float* Kf  = (const float*)d_in[5];
    const float* V0  = (const float*)d_in[6];
    const float* Vf  = (const float*)d_in[7];
    const float* C0  = (const float*)d_in[8];
    const float* C1  = (const float*)d_in[9];
    const float* Cf  = (const float*)d_in[10];
    float* out = (float*)d_out;

    // workspace: TK2 (NH*G*HD float2) | TC2 (G*HD float2) | attn_h
    float2* TK2    = (float2*)d_ws;
    float2* TC2    = TK2 + (size_t)NH*G*HD;
    float*  attn_h = (float*)(TC2 + (size_t)G*HD);

    build_tables<<<384,     128, 0, stream>>>(K0, K1, C0, C1, (float*)TK2, (float*)TC2);
    fused_attn  <<<Z*NH*NPT,256, 0, stream>>>(f, xyz, Wq, Kf, V0, Vf, TK2, attn_h);
    conv_kernel <<<Z*NPT,   256, 0, stream>>>(xyz, TC2, Cf, attn_h, out);
}

// Round 6
// 186.022 us; speedup vs baseline: 3.9983x; 1.0434x over previous
//
#include <hip/hip_runtime.h>
#include <math.h>

// Problem constants (fixed by reference)
#define Z 2
#define NPT 256     // points per batch
#define CHN 16      // channels
#define NH 2        // heads
#define NBK 10      // key/conv radial basis
#define HD 100      // radial hidden width
#define NBV 3       // value radial basis
#define G 2048      // radial table grid points
// Unified table domain [0, VD]. Key/conv radials are exactly 0 beyond
// 5+5/9 (all cosine bases zero); value radial support extends to 7.5
// (basis center 5.0 + half-width 2.5). Beyond VD all three are exactly 0.
#define VD 7.5f

__device__ __forceinline__ float swishf(float x) {
    return x / (1.0f + __expf(-x));
}

// ---------------------------------------------------------------------------
// Kernel 1: build radial tables as interleaved float2 {T[g], T[g+1]}.
// reps: 0,1 = key heads (2-layer); 2 = conv (2-layer); 3,4 = value heads
// (1-layer). 16 grid pts per block; grid = 5*128 = 640 blocks x 128 threads.
// ---------------------------------------------------------------------------
__global__ __launch_bounds__(128)
void build_tables(const float* __restrict__ K0, const float* __restrict__ K1,
                  const float* __restrict__ C0, const float* __restrict__ C1,
                  const float* __restrict__ V0,
                  float* __restrict__ TKf, float* __restrict__ TCf,
                  float* __restrict__ TVf) {
    int bid = blockIdx.x;
    int rep = bid >> 7;              // 0..4
    int g0  = (bid & 127) * 16;
    int t   = threadIdx.x;

    if (rep >= 3) {                  // value heads: 1-layer radial
        const float* W0v = V0 + (rep - 3)*NBV*HD;
        float* Tf = TVf + (size_t)(rep - 3)*2*G*HD;
        if (t < HD) {
            #pragma unroll
            for (int k = 0; k < 16; ++k) {
                int gg = g0 + k;
                float d = gg * (VD / (float)(G-1));
                float s = 0.f;
                #pragma unroll
                for (int q = 0; q < NBV; ++q) {
                    float diff = (d - q*2.5f) * 0.4f;
                    float bq = (fabsf(diff) < 1.0f) ? __cosf(1.57079632679f*diff) : 0.f;
                    s += bq * W0v[q*HD + t];
                }
                float v = swishf(s);
                Tf[2*((size_t)gg*HD + t) + 0] = v;
                if (gg > 0) Tf[2*((size_t)(gg-1)*HD + t) + 1] = v;
            }
        }
        return;
    }

    const float* W0 = (rep == 0) ? K0 : (rep == 1) ? (K0 + NBK*HD) : C0;
    const float* W1 = (rep == 0) ? K1 : (rep == 1) ? (K1 + HD*HD)  : C1;
    float* Tf       = (rep == 0) ? TKf : (rep == 1) ? (TKf + 2*(size_t)G*HD) : TCf;

    __shared__ float s_b10[16][NBK];
    __shared__ __align__(16) float s_h1[HD*16];   // [n][k]

    if (t < 16) {
        float d = (g0 + t) * (VD / (float)(G-1));
        #pragma unroll
        for (int q = 0; q < NBK; ++q) {
            float diff = (d - q*(5.0f/9.0f)) * 1.8f;
            s_b10[t][q] = (fabsf(diff) < 1.0f) ? __cosf(1.57079632679f*diff) : 0.f;
        }
    }
    __syncthreads();
    if (t < HD) {
        int n = t;
        float w[NBK];
        #pragma unroll
        for (int q = 0; q < NBK; ++q) w[q] = W0[q*HD + n];
        #pragma unroll
        for (int k = 0; k < 16; ++k) {
            float s = 0.f;
            #pragma unroll
            for (int q = 0; q < NBK; ++q) s += s_b10[k][q] * w[q];
            s_h1[n*16 + k] = swishf(s);
        }
    }
    __syncthreads();
    if (t < HD) {
        int m = t;
        float acc[16];
        #pragma unroll
        for (int k = 0; k < 16; ++k) acc[k] = 0.f;
        const float* w1 = W1 + m;
        #pragma unroll 2
        for (int n = 0; n < HD; ++n) {
            float w = w1[n*HD];                            // coalesced across m
            const float4* hp = (const float4*)&s_h1[n*16]; // broadcast
            float4 x0 = hp[0], x1 = hp[1], x2 = hp[2], x3 = hp[3];
            acc[0]+=x0.x*w;  acc[1]+=x0.y*w;  acc[2]+=x0.z*w;  acc[3]+=x0.w*w;
            acc[4]+=x1.x*w;  acc[5]+=x1.y*w;  acc[6]+=x1.z*w;  acc[7]+=x1.w*w;
            acc[8]+=x2.x*w;  acc[9]+=x2.y*w;  acc[10]+=x2.z*w; acc[11]+=x2.w*w;
            acc[12]+=x3.x*w; acc[13]+=x3.y*w; acc[14]+=x3.z*w; acc[15]+=x3.w*w;
        }
        #pragma unroll
        for (int k = 0; k < 16; ++k) {
            float v = swishf(acc[k]);
            int gg = g0 + k;
            Tf[2*((size_t)gg*HD + m) + 0] = v;
            if (gg > 0) Tf[2*((size_t)(gg-1)*HD + m) + 1] = v;
        }
    }
}

// ---------------------------------------------------------------------------
// Kernel 2: fused q/Gq + scores + softmax + value-U + Vf epilogue.
// One block per (z,h,a) = 1024 blocks x 256 threads. Both radials via
// table lerp with depth-1 prefetch; paired-shuffle score reduce (7/2b).
// ---------------------------------------------------------------------------
__global__ __launch_bounds__(256, 4)
void fused_attn(const float* __restrict__ f, const float* __restrict__ xyz,
                const float* __restrict__ Wq, const float* __restrict__ Kf,
                const float* __restrict__ Vf,
                const float2* __restrict__ TK2, const float2* __restrict__ TV2,
                float* __restrict__ attn_h) {
    int bid = blockIdx.x;            // (z*NH + h)*NPT + a
    int a  = bid & 255;
    int zh = bid >> 8;
    int h  = zh & 1;
    int z  = zh >> 1;
    int t  = threadIdx.x;

    __shared__ __align__(16) float s_f[NPT*CHN];   // 16384 B
    __shared__ __align__(16) float s_gu[HD*20];    // 8000 B  gq then U
    __shared__ int   s_gi[NPT];                    // 1024 B
    __shared__ float s_fr[NPT];                    // 1024 B
    __shared__ float s_sc[NPT];                    // 1024 B  scores then p
    __shared__ float s_red[8];
    __shared__ float s_red2[256];                  // q early; Vf partials late

    // phase 1: stage features, per-b geometry, q, gq
    {
        const float4* fz = (const float4*)(f + (size_t)z*NPT*CHN);
        float4* sf = (float4*)s_f;
        for (int i = t; i < NPT*CHN/4; i += 256) sf[i] = fz[i];
    }
    {
        float ax = xyz[(z*NPT + a)*3 + 0];
        float ay = xyz[(z*NPT + a)*3 + 1];
        float az = xyz[(z*NPT + a)*3 + 2];
        int b = t;
        float dx = xyz[(z*NPT + b)*3 + 0] - ax;
        float dy = xyz[(z*NPT + b)*3 + 1] - ay;
        float dz = xyz[(z*NPT + b)*3 + 2] - az;
        float d = sqrtf(dx*dx + dy*dy + dz*dz + 1e-12f);
        float fd = d * ((float)(G-1) / VD);
        int   gi = (int)fd;
        float fr = fd - (float)gi;
        if (gi >= G-1) { gi = G-2; fr = 1.0f; }    // beyond support -> exact 0
        s_gi[b] = gi; s_fr[b] = fr;
    }
    __syncthreads();
    if (t < CHN) {       // q[o] = sum_i f[a,i] * Wq[h][o][i]
        float s = 0.f;
        const float* wq = Wq + (h*CHN + t)*CHN;
        #pragma unroll
        for (int i = 0; i < CHN; ++i) s += s_f[a*CHN + i] * wq[i];
        s_red2[t] = s;
    }
    __syncthreads();
    {   // gq[m][j] = sum_i Kf[h][m][i*16+j] * q[i]
        const float* kf = Kf + (size_t)h*HD*256;
        for (int idx = t; idx < HD*CHN; idx += 256) {
            int m = idx >> 4, j = idx & 15;
            float s = 0.f;
            #pragma unroll
            for (int i = 0; i < CHN; ++i) s += kf[m*256 + i*16 + j] * s_red2[i];
            s_gu[m*20 + j] = s;
        }
    }
    __syncthreads();

    // phase 2: scores. wave w owns b in [w*64, w*64+64); lane covers m, m+64.
    {
        int lane = t & 63, w = t >> 6;
        int m2 = lane + 64;
        bool hasm2 = (m2 < HD);
        float gq1[16], gq2[16];
        {
            const float4* gp = (const float4*)&s_gu[lane*20];
            float4 g0 = gp[0], g1 = gp[1], g2 = gp[2], g3 = gp[3];
            gq1[0]=g0.x;  gq1[1]=g0.y;  gq1[2]=g0.z;  gq1[3]=g0.w;
            gq1[4]=g1.x;  gq1[5]=g1.y;  gq1[6]=g1.z;  gq1[7]=g1.w;
            gq1[8]=g2.x;  gq1[9]=g2.y;  gq1[10]=g2.z; gq1[11]=g2.w;
            gq1[12]=g3.x; gq1[13]=g3.y; gq1[14]=g3.z; gq1[15]=g3.w;
        }
        #pragma unroll
        for (int j = 0; j < 16; ++j) gq2[j] = 0.f;
        if (hasm2) {
            const float4* gp = (const float4*)&s_gu[m2*20];
            float4 g0 = gp[0], g1 = gp[1], g2 = gp[2], g3 = gp[3];
            gq2[0]=g0.x;  gq2[1]=g0.y;  gq2[2]=g0.z;  gq2[3]=g0.w;
            gq2[4]=g1.x;  gq2[5]=g1.y;  gq2[6]=g1.z;  gq2[7]=g1.w;
            gq2[8]=g2.x;  gq2[9]=g2.y;  gq2[10]=g2.z; gq2[11]=g2.w;
            gq2[12]=g3.x; gq2[13]=g3.y; gq2[14]=g3.z; gq2[15]=g3.w;
        }
        const float2* tk = TK2 + (size_t)h*G*HD;
        int bbase = w*64;
        // depth-1 prefetch of the 2-b pair's table rows
        float2 ta0, tb0, ta1, tb1;
        {
            int g0i = s_gi[bbase], g1i = s_gi[bbase+1];
            ta0 = tk[(size_t)g0i*HD + lane];
            tb0 = hasm2 ? tk[(size_t)g0i*HD + m2] : make_float2(0.f, 0.f);
            ta1 = tk[(size_t)g1i*HD + lane];
            tb1 = hasm2 ? tk[(size_t)g1i*HD + m2] : make_float2(0.f, 0.f);
        }
        #pragma unroll 1
        for (int bb = 0; bb < 64; bb += 2) {
            int b0 = bbase + bb, b1 = b0 + 1;
            float fr0 = s_fr[b0], fr1 = s_fr[b1];
            float2 ca0 = ta0, cb0 = tb0, ca1 = ta1, cb1 = tb1;
            if (bb + 2 < 64) {
                int gn0 = s_gi[b0 + 2], gn1 = s_gi[b0 + 3];
                ta0 = tk[(size_t)gn0*HD + lane];
                tb0 = hasm2 ? tk[(size_t)gn0*HD + m2] : make_float2(0.f, 0.f);
                ta1 = tk[(size_t)gn1*HD + lane];
                tb1 = hasm2 ? tk[(size_t)gn1*HD + m2] : make_float2(0.f, 0.f);
            }
            float h2a0 = ca0.x + fr0*(ca0.y - ca0.x);
            float h2b0 = cb0.x + fr0*(cb0.y - cb0.x);
            float h2a1 = ca1.x + fr1*(ca1.y - ca1.x);
            float h2b1 = cb1.x + fr1*(cb1.y - cb1.x);
            const float4* fp0 = (const float4*)&s_f[b0*CHN];
            const float4* fp1 = (const float4*)&s_f[b1*CHN];
            float4 x0 = fp0[0], x1 = fp0[1], x2 = fp0[2], x3 = fp0[3];
            float4 y0 = fp1[0], y1 = fp1[1], y2 = fp1[2], y3 = fp1[3];
            float gfa0 = gq1[0]*x0.x + gq1[1]*x0.y + gq1[2]*x0.z + gq1[3]*x0.w
                       + gq1[4]*x1.x + gq1[5]*x1.y + gq1[6]*x1.z + gq1[7]*x1.w
                       + gq1[8]*x2.x + gq1[9]*x2.y + gq1[10]*x2.z + gq1[11]*x2.w
                       + gq1[12]*x3.x + gq1[13]*x3.y + gq1[14]*x3.z + gq1[15]*x3.w;
            float gfb0 = gq2[0]*x0.x + gq2[1]*x0.y + gq2[2]*x0.z + gq2[3]*x0.w
                       + gq2[4]*x1.x + gq2[5]*x1.y + gq2[6]*x1.z + gq2[7]*x1.w
                       + gq2[8]*x2.x + gq2[9]*x2.y + gq2[10]*x2.z + gq2[11]*x2.w
                       + gq2[12]*x3.x + gq2[13]*x3.y + gq2[14]*x3.z + gq2[15]*x3.w;
            float gfa1 = gq1[0]*y0.x + gq1[1]*y0.y + gq1[2]*y0.z + gq1[3]*y0.w
                       + gq1[4]*y1.x + gq1[5]*y1.y + gq1[6]*y1.z + gq1[7]*y1.w
                       + gq1[8]*y2.x + gq1[9]*y2.y + gq1[10]*y2.z + gq1[11]*y2.w
                       + gq1[12]*y3.x + gq1[13]*y3.y + gq1[14]*y3.z + gq1[15]*y3.w;
            float gfb1 = gq2[0]*y0.x + gq2[1]*y0.y + gq2[2]*y0.z + gq2[3]*y0.w
                       + gq2[4]*y1.x + gq2[5]*y1.y + gq2[6]*y1.z + gq2[7]*y1.w
                       + gq2[8]*y2.x + gq2[9]*y2.y + gq2[10]*y2.z + gq2[11]*y2.w
                       + gq2[12]*y3.x + gq2[13]*y3.y + gq2[14]*y3.z + gq2[15]*y3.w;
            float pp0 = h2a0*gfa0 + h2b0*gfb0;
            float pp1 = h2a1*gfa1 + h2b1*gfb1;
            // packed butterfly: 7 shuffles reduce both pp0 and pp1
            float u0 = __shfl_xor(pp0, 32);
            float u1 = __shfl_xor(pp1, 32);
            float mm = (lane < 32) ? (pp0 + u0) : (pp1 + u1);
            mm += __shfl_xor(mm, 16);
            mm += __shfl_xor(mm, 8);
            mm += __shfl_xor(mm, 4);
            mm += __shfl_xor(mm, 2);
            mm += __shfl_xor(mm, 1);
            if (lane == 0)  s_sc[b0] = mm * (1.0f/16.0f);
            if (lane == 32) s_sc[b1] = mm * (1.0f/16.0f);
        }
    }
    __syncthreads();

    // phase 3: softmax over 256 scores
    {
        float v = s_sc[t];
        float mx = v;
        #pragma unroll
        for (int off = 32; off >= 1; off >>= 1) mx = fmaxf(mx, __shfl_xor(mx, off));
        int wid = t >> 6;
        if ((t & 63) == 0) s_red[wid] = mx;
        __syncthreads();
        mx = fmaxf(fmaxf(s_red[0], s_red[1]), fmaxf(s_red[2], s_red[3]));
        float e = __expf(v - mx);
        float s = e;
        #pragma unroll
        for (int off = 32; off >= 1; off >>= 1) s += __shfl_xor(s, off);
        if ((t & 63) == 0) s_red[4 + wid] = s;
        __syncthreads();
        float tot = s_red[4] + s_red[5] + s_red[6] + s_red[7];
        s_sc[t] = e / tot;
    }
    __syncthreads();

    // phase 4: U[m,j] = sum_b p_b * h1v(d_b)[m] * f[b,j]  via TV lerp
    {
        int mh = t & 127, half = t >> 7;
        float U[16];
        #pragma unroll
        for (int j = 0; j < 16; ++j) U[j] = 0.f;
        if (mh < HD) {
            const float2* tv = TV2 + (size_t)h*G*HD;
            int bbase = half*128;
            float2 tc = tv[(size_t)s_gi[bbase]*HD + mh];
            #pragma unroll 2
            for (int bb = 0; bb < 128; ++bb) {
                int b = bbase + bb;
                float fr = s_fr[b];
                float2 cur = tc;
                if (bb + 1 < 128) tc = tv[(size_t)s_gi[b+1]*HD + mh];
                float hv = cur.x + fr*(cur.y - cur.x);
                float t1 = s_sc[b] * hv;
                const float4* fp = (const float4*)&s_f[b*CHN];
                float4 f0 = fp[0], f1 = fp[1], f2 = fp[2], f3 = fp[3];
                U[0]+=t1*f0.x;  U[1]+=t1*f0.y;  U[2]+=t1*f0.z;  U[3]+=t1*f0.w;
                U[4]+=t1*f1.x;  U[5]+=t1*f1.y;  U[6]+=t1*f1.z;  U[7]+=t1*f1.w;
                U[8]+=t1*f2.x;  U[9]+=t1*f2.y;  U[10]+=t1*f2.z; U[11]+=t1*f2.w;
                U[12]+=t1*f3.x; U[13]+=t1*f3.y; U[14]+=t1*f3.z; U[15]+=t1*f3.w;
            }
        }
        if (half == 1 && mh < HD) {
            #pragma unroll
            for (int j = 0; j < 16; ++j) s_gu[mh*20 + j] = U[j];
        }
        __syncthreads();
        if (half == 0 && mh < HD) {
            #pragma unroll
            for (int j = 0; j < 16; ++j) s_gu[mh*20 + j] += U[j];
        }
    }
    __syncthreads();
    {   // epilogue: attn_h[bid][i] = sum_{m,j} U[m,j] * Vf[h][m][i*16+j]
        int i = t & 15, ms = t >> 4;
        float acc = 0.f;
        for (int m = ms; m < HD; m += 16) {
            const float* vf = Vf + ((size_t)h*HD + m)*256 + i*16;
            const float* Um = &s_gu[m*20];
            #pragma unroll
            for (int j = 0; j < 16; ++j) acc += Um[j] * vf[j];
        }
        s_red2[ms*16 + i] = acc;
    }
    __syncthreads();
    if (t < 16) {
        float s = 0.f;
        #pragma unroll
        for (int ms = 0; ms < 16; ++ms) s += s_red2[ms*16 + t];
        attn_h[(size_t)bid*CHN + t] = s;
    }
}

// ---------------------------------------------------------------------------
// Kernel 3: final conv, one block per (z,a,b-half) = 1024 blocks.
// Partial U over 128 b's, contract with Cf, atomicAdd 16 floats into out.
// ---------------------------------------------------------------------------
__global__ __launch_bounds__(256)
void conv_kernel(const float* __restrict__ xyz, const float2* __restrict__ TC2,
                 const float* __restrict__ Cf, const float* __restrict__ attn_h,
                 float* __restrict__ out) {
    int bid = blockIdx.x;
    int bh  = bid & 1;
    int za  = bid >> 1;
    int z   = za >> 8;
    int b0  = bh * 128;
    int t   = threadIdx.x;

    __shared__ __align__(16) float s_ao[128*CHN];  // 8192 B head-summed attn
    __shared__ float s_U[HD*20];                   // 8000 B
    __shared__ int   s_gi[128];
    __shared__ float s_fr[128];
    __shared__ float s_red2[256];

    for (int idx = t; idx < 128*CHN; idx += 256) {
        s_ao[idx] = attn_h[(size_t)(z*NH + 0)*NPT*CHN + b0*CHN + idx]
                  + attn_h[(size_t)(z*NH + 1)*NPT*CHN + b0*CHN + idx];
    }
    if (t < 128) {
        int b = b0 + t;
        float dx = xyz[(z*NPT+b)*3+0] - xyz[za*3+0];
        float dy = xyz[(z*NPT+b)*3+1] - xyz[za*3+1];
        float dz = xyz[(z*NPT+b)*3+2] - xyz[za*3+2];
        float d = sqrtf(dx*dx + dy*dy + dz*dz + 1e-12f);
        float fd = d * ((float)(G-1) / VD);
        int   gi = (int)fd;
        float fr = fd - (float)gi;
        if (gi >= G-1) { gi = G-2; fr = 1.0f; }
        s_gi[t] = gi; s_fr[t] = fr;
    }
    __syncthreads();
    int mh = t & 127, half = t >> 7;
    float U[16];
    #pragma unroll
    for (int j = 0; j < 16; ++j) U[j] = 0.f;
    if (mh < HD) {
        int lb = half*64;
        float2 tc = TC2[(size_t)s_gi[lb]*HD + mh];
        #pragma unroll 2
        for (int bb = 0; bb < 64; ++bb) {
            int bl = lb + bb;
            float fr = s_fr[bl];
            float2 cur = tc;
            if (bb + 1 < 64) tc = TC2[(size_t)s_gi[bl+1]*HD + mh];
            float h2 = cur.x + fr*(cur.y - cur.x);
            const float4* ap = (const float4*)&s_ao[bl*CHN];
            float4 a0 = ap[0], a1 = ap[1], a2 = ap[2], a3 = ap[3];
            U[0]+=h2*a0.x;  U[1]+=h2*a0.y;  U[2]+=h2*a0.z;  U[3]+=h2*a0.w;
            U[4]+=h2*a1.x;  U[5]+=h2*a1.y;  U[6]+=h2*a1.z;  U[7]+=h2*a1.w;
            U[8]+=h2*a2.x;  U[9]+=h2*a2.y;  U[10]+=h2*a2.z; U[11]+=h2*a2.w;
            U[12]+=h2*a3.x; U[13]+=h2*a3.y; U[14]+=h2*a3.z; U[15]+=h2*a3.w;
        }
    }
    if (half == 1 && mh < HD) {
        #pragma unroll
        for (int j = 0; j < 16; ++j) s_U[mh*20 + j] = U[j];
    }
    __syncthreads();
    if (half == 0 && mh < HD) {
        #pragma unroll
        for (int j = 0; j < 16; ++j) s_U[mh*20 + j] += U[j];
    }
    __syncthreads();
    {
        int i = t & 15, ms = t >> 4;
        float acc = 0.f;
        for (int m = ms; m < HD; m += 16) {
            const float* cf = Cf + (size_t)m*256 + i*16;
            const float* Um = &s_U[m*20];
            #pragma unroll
            for (int j = 0; j < 16; ++j) acc += Um[j] * cf[j];
        }
        s_red2[ms*16 + i] = acc;
    }
    __syncthreads();
    if (t < 16) {
        float s = 0.f;
        #pragma unroll
        for (int ms = 0; ms < 16; ++ms) s += s_red2[ms*16 + t];
        atomicAdd(out + (size_t)za*CHN + t, s);
    }
}

// ---------------------------------------------------------------------------
extern "C" void kernel_launch(void* const* d_in, const int* in_sizes, int n_in,
                              void* d_out, int out_size, void* d_ws, size_t ws_size,
                              hipStream_t stream) {
    const float* f   = (const float*)d_in[0];
    const float* xyz = (const float*)d_in[1];
    const float* Wq  = (const float*)d_in[2];
    const float* K0  = (const float*)d_in[3];
    const float* K1  = (const float*)d_in[4];
    const float* Kf  = (const float*)d_in[5];
    const float* V0  = (const float*)d_in[6];
    const float* Vf  = (const float*)d_in[7];
    const float* C0  = (const float*)d_in[8];
    const float* C1  = (const float*)d_in[9];
    const float* Cf  = (const float*)d_in[10];
    float* out = (float*)d_out;

    // workspace: TK2 | TC2 | TV2 (float2 tables) | attn_h
    float2* TK2    = (float2*)d_ws;
    float2* TC2    = TK2 + (size_t)NH*G*HD;
    float2* TV2    = TC2 + (size_t)G*HD;
    float*  attn_h = (float*)(TV2 + (size_t)NH*G*HD);

    hipMemsetAsync(out, 0, (size_t)out_size*sizeof(float), stream);
    build_tables<<<640,      128, 0, stream>>>(K0, K1, C0, C1, V0,
                                               (float*)TK2, (float*)TC2, (float*)TV2);
    fused_attn  <<<Z*NH*NPT, 256, 0, stream>>>(f, xyz, Wq, Kf, Vf, TK2, TV2, attn_h);
    conv_kernel <<<Z*NPT*2,  256, 0, stream>>>(xyz, TC2, Cf, attn_h, out);
}

// Round 7
// 176.139 us; speedup vs baseline: 4.2226x; 1.0561x over previous
//
#include <hip/hip_runtime.h>
#include <math.h>

// Problem constants (fixed by reference)
#define Z 2
#define NPT 256     // points per batch
#define CHN 16      // channels
#define NH 2        // heads
#define NBK 10      // key/conv radial basis
#define HD 100      // radial hidden width
#define NBV 3       // value radial basis
#define G 512       // radial table grid points (L2-resident: all tables ~2 MB)
// Unified table domain [0, VD]. Key/conv radials are exactly 0 beyond
// 5+5/9 (all cosine bases zero); value radial support extends to 7.5.
// At d = VD all three radials are exactly 0, so the gi>=G-1 clamp is exact.
#define VD 7.5f

__device__ __forceinline__ float swishf(float x) {
    return x / (1.0f + __expf(-x));
}

// ---------------------------------------------------------------------------
// Kernel 1: build radial tables as interleaved float2 {T[g], T[g+1]};
// also zeroes d_out (block 0) so conv can atomicAdd without a memset node.
// reps: 0,1 = key heads (2-layer); 2 = conv (2-layer); 3,4 = value (1-layer).
// 16 grid pts per block; grid = 5*32 = 160 blocks x 128 threads.
// ---------------------------------------------------------------------------
__global__ __launch_bounds__(128)
void build_tables(const float* __restrict__ K0, const float* __restrict__ K1,
                  const float* __restrict__ C0, const float* __restrict__ C1,
                  const float* __restrict__ V0,
                  float* __restrict__ TKf, float* __restrict__ TCf,
                  float* __restrict__ TVf, float* __restrict__ out_zero) {
    int bid = blockIdx.x;
    int rep = bid >> 5;              // 0..4
    int g0  = (bid & 31) * 16;
    int t   = threadIdx.x;

    if (bid == 0) {                  // zero d_out: Z*NPT*CHN = 8192 floats
        float4* o4 = (float4*)out_zero;
        #pragma unroll
        for (int k = 0; k < 16; ++k) o4[k*128 + t] = make_float4(0.f,0.f,0.f,0.f);
    }

    if (rep >= 3) {                  // value heads: 1-layer radial
        const float* W0v = V0 + (rep - 3)*NBV*HD;
        float* Tf = TVf + (size_t)(rep - 3)*2*G*HD;
        if (t < HD) {
            #pragma unroll
            for (int k = 0; k < 16; ++k) {
                int gg = g0 + k;
                float d = gg * (VD / (float)(G-1));
                float s = 0.f;
                #pragma unroll
                for (int q = 0; q < NBV; ++q) {
                    float diff = (d - q*2.5f) * 0.4f;
                    float bq = (fabsf(diff) < 1.0f) ? __cosf(1.57079632679f*diff) : 0.f;
                    s += bq * W0v[q*HD + t];
                }
                float v = swishf(s);
                Tf[2*((size_t)gg*HD + t) + 0] = v;
                if (gg > 0) Tf[2*((size_t)(gg-1)*HD + t) + 1] = v;
            }
        }
        return;
    }

    const float* W0 = (rep == 0) ? K0 : (rep == 1) ? (K0 + NBK*HD) : C0;
    const float* W1 = (rep == 0) ? K1 : (rep == 1) ? (K1 + HD*HD)  : C1;
    float* Tf       = (rep == 0) ? TKf : (rep == 1) ? (TKf + 2*(size_t)G*HD) : TCf;

    __shared__ float s_b10[16][NBK];
    __shared__ __align__(16) float s_h1[HD*16];   // [n][k]

    if (t < 16) {
        float d = (g0 + t) * (VD / (float)(G-1));
        #pragma unroll
        for (int q = 0; q < NBK; ++q) {
            float diff = (d - q*(5.0f/9.0f)) * 1.8f;
            s_b10[t][q] = (fabsf(diff) < 1.0f) ? __cosf(1.57079632679f*diff) : 0.f;
        }
    }
    __syncthreads();
    if (t < HD) {
        int n = t;
        float w[NBK];
        #pragma unroll
        for (int q = 0; q < NBK; ++q) w[q] = W0[q*HD + n];
        #pragma unroll
        for (int k = 0; k < 16; ++k) {
            float s = 0.f;
            #pragma unroll
            for (int q = 0; q < NBK; ++q) s += s_b10[k][q] * w[q];
            s_h1[n*16 + k] = swishf(s);
        }
    }
    __syncthreads();
    if (t < HD) {
        int m = t;
        float acc[16];
        #pragma unroll
        for (int k = 0; k < 16; ++k) acc[k] = 0.f;
        const float* w1 = W1 + m;
        #pragma unroll 2
        for (int n = 0; n < HD; ++n) {
            float w = w1[n*HD];                            // coalesced across m
            const float4* hp = (const float4*)&s_h1[n*16]; // broadcast
            float4 x0 = hp[0], x1 = hp[1], x2 = hp[2], x3 = hp[3];
            acc[0]+=x0.x*w;  acc[1]+=x0.y*w;  acc[2]+=x0.z*w;  acc[3]+=x0.w*w;
            acc[4]+=x1.x*w;  acc[5]+=x1.y*w;  acc[6]+=x1.z*w;  acc[7]+=x1.w*w;
            acc[8]+=x2.x*w;  acc[9]+=x2.y*w;  acc[10]+=x2.z*w; acc[11]+=x2.w*w;
            acc[12]+=x3.x*w; acc[13]+=x3.y*w; acc[14]+=x3.z*w; acc[15]+=x3.w*w;
        }
        #pragma unroll
        for (int k = 0; k < 16; ++k) {
            float v = swishf(acc[k]);
            int gg = g0 + k;
            Tf[2*((size_t)gg*HD + m) + 0] = v;
            if (gg > 0) Tf[2*((size_t)(gg-1)*HD + m) + 1] = v;
        }
    }
}

// ---------------------------------------------------------------------------
// Kernel 2: fused q/Gq + scores + softmax + value-U + Vf epilogue.
// One block per (z,h,a) = 1024 blocks x 256 threads. Both radials via
// L2-resident table lerp with depth-1 prefetch; paired-shuffle score reduce.
// ---------------------------------------------------------------------------
__global__ __launch_bounds__(256, 4)
void fused_attn(const float* __restrict__ f, const float* __restrict__ xyz,
                const float* __restrict__ Wq, const float* __restrict__ Kf,
                const float* __restrict__ Vf,
                const float2* __restrict__ TK2, const float2* __restrict__ TV2,
                float* __restrict__ attn_h) {
    int bid = blockIdx.x;            // (z*NH + h)*NPT + a
    int a  = bid & 255;
    int zh = bid >> 8;
    int h  = zh & 1;
    int z  = zh >> 1;
    int t  = threadIdx.x;

    __shared__ __align__(16) float s_f[NPT*CHN];   // 16384 B
    __shared__ __align__(16) float s_gu[HD*20];    // 8000 B  gq then U
    __shared__ int   s_gi[NPT];                    // 1024 B
    __shared__ float s_fr[NPT];                    // 1024 B
    __shared__ float s_sc[NPT];                    // 1024 B  scores then p
    __shared__ float s_red[8];
    __shared__ float s_red2[256];                  // q early; Vf partials late

    // phase 1: stage features, per-b geometry, q, gq
    {
        const float4* fz = (const float4*)(f + (size_t)z*NPT*CHN);
        float4* sf = (float4*)s_f;
        for (int i = t; i < NPT*CHN/4; i += 256) sf[i] = fz[i];
    }
    {
        float ax = xyz[(z*NPT + a)*3 + 0];
        float ay = xyz[(z*NPT + a)*3 + 1];
        float az = xyz[(z*NPT + a)*3 + 2];
        int b = t;
        float dx = xyz[(z*NPT + b)*3 + 0] - ax;
        float dy = xyz[(z*NPT + b)*3 + 1] - ay;
        float dz = xyz[(z*NPT + b)*3 + 2] - az;
        float d = sqrtf(dx*dx + dy*dy + dz*dz + 1e-12f);
        float fd = d * ((float)(G-1) / VD);
        int   gi = (int)fd;
        float fr = fd - (float)gi;
        if (gi >= G-1) { gi = G-2; fr = 1.0f; }    // beyond support -> exact 0
        s_gi[b] = gi; s_fr[b] = fr;
    }
    __syncthreads();
    if (t < CHN) {       // q[o] = sum_i f[a,i] * Wq[h][o][i]
        float s = 0.f;
        const float* wq = Wq + (h*CHN + t)*CHN;
        #pragma unroll
        for (int i = 0; i < CHN; ++i) s += s_f[a*CHN + i] * wq[i];
        s_red2[t] = s;
    }
    __syncthreads();
    {   // gq[m][j] = sum_i Kf[h][m][i*16+j] * q[i]
        const float* kf = Kf + (size_t)h*HD*256;
        for (int idx = t; idx < HD*CHN; idx += 256) {
            int m = idx >> 4, j = idx & 15;
            float s = 0.f;
            #pragma unroll
            for (int i = 0; i < CHN; ++i) s += kf[m*256 + i*16 + j] * s_red2[i];
            s_gu[m*20 + j] = s;
        }
    }
    __syncthreads();

    // phase 2: scores. wave w owns b in [w*64, w*64+64); lane covers m, m+64.
    {
        int lane = t & 63, w = t >> 6;
        int m2 = lane + 64;
        bool hasm2 = (m2 < HD);
        float gq1[16], gq2[16];
        {
            const float4* gp = (const float4*)&s_gu[lane*20];
            float4 g0 = gp[0], g1 = gp[1], g2 = gp[2], g3 = gp[3];
            gq1[0]=g0.x;  gq1[1]=g0.y;  gq1[2]=g0.z;  gq1[3]=g0.w;
            gq1[4]=g1.x;  gq1[5]=g1.y;  gq1[6]=g1.z;  gq1[7]=g1.w;
            gq1[8]=g2.x;  gq1[9]=g2.y;  gq1[10]=g2.z; gq1[11]=g2.w;
            gq1[12]=g3.x; gq1[13]=g3.y; gq1[14]=g3.z; gq1[15]=g3.w;
        }
        #pragma unroll
        for (int j = 0; j < 16; ++j) gq2[j] = 0.f;
        if (hasm2) {
            const float4* gp = (const float4*)&s_gu[m2*20];
            float4 g0 = gp[0], g1 = gp[1], g2 = gp[2], g3 = gp[3];
            gq2[0]=g0.x;  gq2[1]=g0.y;  gq2[2]=g0.z;  gq2[3]=g0.w;
            gq2[4]=g1.x;  gq2[5]=g1.y;  gq2[6]=g1.z;  gq2[7]=g1.w;
            gq2[8]=g2.x;  gq2[9]=g2.y;  gq2[10]=g2.z; gq2[11]=g2.w;
            gq2[12]=g3.x; gq2[13]=g3.y; gq2[14]=g3.z; gq2[15]=g3.w;
        }
        const float2* tk = TK2 + (size_t)h*G*HD;
        int bbase = w*64;
        float2 ta0, tb0, ta1, tb1;
        {
            int g0i = s_gi[bbase], g1i = s_gi[bbase+1];
            ta0 = tk[(size_t)g0i*HD + lane];
            tb0 = hasm2 ? tk[(size_t)g0i*HD + m2] : make_float2(0.f, 0.f);
            ta1 = tk[(size_t)g1i*HD + lane];
            tb1 = hasm2 ? tk[(size_t)g1i*HD + m2] : make_float2(0.f, 0.f);
        }
        #pragma unroll 1
        for (int bb = 0; bb < 64; bb += 2) {
            int b0 = bbase + bb, b1 = b0 + 1;
            float fr0 = s_fr[b0], fr1 = s_fr[b1];
            float2 ca0 = ta0, cb0 = tb0, ca1 = ta1, cb1 = tb1;
            if (bb + 2 < 64) {
                int gn0 = s_gi[b0 + 2], gn1 = s_gi[b0 + 3];
                ta0 = tk[(size_t)gn0*HD + lane];
                tb0 = hasm2 ? tk[(size_t)gn0*HD + m2] : make_float2(0.f, 0.f);
                ta1 = tk[(size_t)gn1*HD + lane];
                tb1 = hasm2 ? tk[(size_t)gn1*HD + m2] : make_float2(0.f, 0.f);
            }
            float h2a0 = ca0.x + fr0*(ca0.y - ca0.x);
            float h2b0 = cb0.x + fr0*(cb0.y - cb0.x);
            float h2a1 = ca1.x + fr1*(ca1.y - ca1.x);
            float h2b1 = cb1.x + fr1*(cb1.y - cb1.x);
            const float4* fp0 = (const float4*)&s_f[b0*CHN];
            const float4* fp1 = (const float4*)&s_f[b1*CHN];
            float4 x0 = fp0[0], x1 = fp0[1], x2 = fp0[2], x3 = fp0[3];
            float4 y0 = fp1[0], y1 = fp1[1], y2 = fp1[2], y3 = fp1[3];
            float gfa0 = gq1[0]*x0.x + gq1[1]*x0.y + gq1[2]*x0.z + gq1[3]*x0.w
                       + gq1[4]*x1.x + gq1[5]*x1.y + gq1[6]*x1.z + gq1[7]*x1.w
                       + gq1[8]*x2.x + gq1[9]*x2.y + gq1[10]*x2.z + gq1[11]*x2.w
                       + gq1[12]*x3.x + gq1[13]*x3.y + gq1[14]*x3.z + gq1[15]*x3.w;
            float gfb0 = gq2[0]*x0.x + gq2[1]*x0.y + gq2[2]*x0.z + gq2[3]*x0.w
                       + gq2[4]*x1.x + gq2[5]*x1.y + gq2[6]*x1.z + gq2[7]*x1.w
                       + gq2[8]*x2.x + gq2[9]*x2.y + gq2[10]*x2.z + gq2[11]*x2.w
                       + gq2[12]*x3.x + gq2[13]*x3.y + gq2[14]*x3.z + gq2[15]*x3.w;
            float gfa1 = gq1[0]*y0.x + gq1[1]*y0.y + gq1[2]*y0.z + gq1[3]*y0.w
                       + gq1[4]*y1.x + gq1[5]*y1.y + gq1[6]*y1.z + gq1[7]*y1.w
                       + gq1[8]*y2.x + gq1[9]*y2.y + gq1[10]*y2.z + gq1[11]*y2.w
                       + gq1[12]*y3.x + gq1[13]*y3.y + gq1[14]*y3.z + gq1[15]*y3.w;
            float gfb1 = gq2[0]*y0.x + gq2[1]*y0.y + gq2[2]*y0.z + gq2[3]*y0.w
                       + gq2[4]*y1.x + gq2[5]*y1.y + gq2[6]*y1.z + gq2[7]*y1.w
                       + gq2[8]*y2.x + gq2[9]*y2.y + gq2[10]*y2.z + gq2[11]*y2.w
                       + gq2[12]*y3.x + gq2[13]*y3.y + gq2[14]*y3.z + gq2[15]*y3.w;
            float pp0 = h2a0*gfa0 + h2b0*gfb0;
            float pp1 = h2a1*gfa1 + h2b1*gfb1;
            float u0 = __shfl_xor(pp0, 32);
            float u1 = __shfl_xor(pp1, 32);
            float mm = (lane < 32) ? (pp0 + u0) : (pp1 + u1);
            mm += __shfl_xor(mm, 16);
            mm += __shfl_xor(mm, 8);
            mm += __shfl_xor(mm, 4);
            mm += __shfl_xor(mm, 2);
            mm += __shfl_xor(mm, 1);
            if (lane == 0)  s_sc[b0] = mm * (1.0f/16.0f);
            if (lane == 32) s_sc[b1] = mm * (1.0f/16.0f);
        }
    }
    __syncthreads();

    // phase 3: softmax over 256 scores
    {
        float v = s_sc[t];
        float mx = v;
        #pragma unroll
        for (int off = 32; off >= 1; off >>= 1) mx = fmaxf(mx, __shfl_xor(mx, off));
        int wid = t >> 6;
        if ((t & 63) == 0) s_red[wid] = mx;
        __syncthreads();
        mx = fmaxf(fmaxf(s_red[0], s_red[1]), fmaxf(s_red[2], s_red[3]));
        float e = __expf(v - mx);
        float s = e;
        #pragma unroll
        for (int off = 32; off >= 1; off >>= 1) s += __shfl_xor(s, off);
        if ((t & 63) == 0) s_red[4 + wid] = s;
        __syncthreads();
        float tot = s_red[4] + s_red[5] + s_red[6] + s_red[7];
        s_sc[t] = e / tot;
    }
    __syncthreads();

    // phase 4: U[m,j] = sum_b p_b * h1v(d_b)[m] * f[b,j]  via TV lerp
    {
        int mh = t & 127, half = t >> 7;
        float U[16];
        #pragma unroll
        for (int j = 0; j < 16; ++j) U[j] = 0.f;
        if (mh < HD) {
            const float2* tv = TV2 + (size_t)h*G*HD;
            int bbase = half*128;
            float2 tc = tv[(size_t)s_gi[bbase]*HD + mh];
            #pragma unroll 2
            for (int bb = 0; bb < 128; ++bb) {
                int b = bbase + bb;
                float fr = s_fr[b];
                float2 cur = tc;
                if (bb + 1 < 128) tc = tv[(size_t)s_gi[b+1]*HD + mh];
                float hv = cur.x + fr*(cur.y - cur.x);
                float t1 = s_sc[b] * hv;
                const float4* fp = (const float4*)&s_f[b*CHN];
                float4 f0 = fp[0], f1 = fp[1], f2 = fp[2], f3 = fp[3];
                U[0]+=t1*f0.x;  U[1]+=t1*f0.y;  U[2]+=t1*f0.z;  U[3]+=t1*f0.w;
                U[4]+=t1*f1.x;  U[5]+=t1*f1.y;  U[6]+=t1*f1.z;  U[7]+=t1*f1.w;
                U[8]+=t1*f2.x;  U[9]+=t1*f2.y;  U[10]+=t1*f2.z; U[11]+=t1*f2.w;
                U[12]+=t1*f3.x; U[13]+=t1*f3.y; U[14]+=t1*f3.z; U[15]+=t1*f3.w;
            }
        }
        if (half == 1 && mh < HD) {
            #pragma unroll
            for (int j = 0; j < 16; ++j) s_gu[mh*20 + j] = U[j];
        }
        __syncthreads();
        if (half == 0 && mh < HD) {
            #pragma unroll
            for (int j = 0; j < 16; ++j) s_gu[mh*20 + j] += U[j];
        }
    }
    __syncthreads();
    {   // epilogue: attn_h[bid][i] = sum_{m,j} U[m,j] * Vf[h][m][i*16+j]
        int i = t & 15, ms = t >> 4;
        float acc = 0.f;
        for (int m = ms; m < HD; m += 16) {
            const float* vf = Vf + ((size_t)h*HD + m)*256 + i*16;
            const float* Um = &s_gu[m*20];
            #pragma unroll
            for (int j = 0; j < 16; ++j) acc += Um[j] * vf[j];
        }
        s_red2[ms*16 + i] = acc;
    }
    __syncthreads();
    if (t < 16) {
        float s = 0.f;
        #pragma unroll
        for (int ms = 0; ms < 16; ++ms) s += s_red2[ms*16 + t];
        attn_h[(size_t)bid*CHN + t] = s;
    }
}

// ---------------------------------------------------------------------------
// Kernel 3: final conv, one block per (z,a,b-half) = 1024 blocks.
// Partial U over 128 b's, contract with Cf, atomicAdd 16 floats into out
// (out zeroed by build_tables at graph start).
// ---------------------------------------------------------------------------
__global__ __launch_bounds__(256)
void conv_kernel(const float* __restrict__ xyz, const float2* __restrict__ TC2,
                 const float* __restrict__ Cf, const float* __restrict__ attn_h,
                 float* __restrict__ out) {
    int bid = blockIdx.x;
    int bh  = bid & 1;
    int za  = bid >> 1;
    int z   = za >> 8;
    int b0  = bh * 128;
    int t   = threadIdx.x;

    __shared__ __align__(16) float s_ao[128*CHN];  // 8192 B head-summed attn
    __shared__ float s_U[HD*20];                   // 8000 B
    __shared__ int   s_gi[128];
    __shared__ float s_fr[128];
    __shared__ float s_red2[256];

    for (int idx = t; idx < 128*CHN; idx += 256) {
        s_ao[idx] = attn_h[(size_t)(z*NH + 0)*NPT*CHN + b0*CHN + idx]
                  + attn_h[(size_t)(z*NH + 1)*NPT*CHN + b0*CHN + idx];
    }
    if (t < 128) {
        int b = b0 + t;
        float dx = xyz[(z*NPT+b)*3+0] - xyz[za*3+0];
        float dy = xyz[(z*NPT+b)*3+1] - xyz[za*3+1];
        float dz = xyz[(z*NPT+b)*3+2] - xyz[za*3+2];
        float d = sqrtf(dx*dx + dy*dy + dz*dz + 1e-12f);
        float fd = d * ((float)(G-1) / VD);
        int   gi = (int)fd;
        float fr = fd - (float)gi;
        if (gi >= G-1) { gi = G-2; fr = 1.0f; }
        s_gi[t] = gi; s_fr[t] = fr;
    }
    __syncthreads();
    int mh = t & 127, half = t >> 7;
    float U[16];
    #pragma unroll
    for (int j = 0; j < 16; ++j) U[j] = 0.f;
    if (mh < HD) {
        int lb = half*64;
        float2 tc = TC2[(size_t)s_gi[lb]*HD + mh];
        #pragma unroll 2
        for (int bb = 0; bb < 64; ++bb) {
            int bl = lb + bb;
            float fr = s_fr[bl];
            float2 cur = tc;
            if (bb + 1 < 64) tc = TC2[(size_t)s_gi[bl+1]*HD + mh];
            float h2 = cur.x + fr*(cur.y - cur.x);
            const float4* ap = (const float4*)&s_ao[bl*CHN];
            float4 a0 = ap[0], a1 = ap[1], a2 = ap[2], a3 = ap[3];
            U[0]+=h2*a0.x;  U[1]+=h2*a0.y;  U[2]+=h2*a0.z;  U[3]+=h2*a0.w;
            U[4]+=h2*a1.x;  U[5]+=h2*a1.y;  U[6]+=h2*a1.z;  U[7]+=h2*a1.w;
            U[8]+=h2*a2.x;  U[9]+=h2*a2.y;  U[10]+=h2*a2.z; U[11]+=h2*a2.w;
            U[12]+=h2*a3.x; U[13]+=h2*a3.y; U[14]+=h2*a3.z; U[15]+=h2*a3.w;
        }
    }
    if (half == 1 && mh < HD) {
        #pragma unroll
        for (int j = 0; j < 16; ++j) s_U[mh*20 + j] = U[j];
    }
    __syncthreads();
    if (half == 0 && mh < HD) {
        #pragma unroll
        for (int j = 0; j < 16; ++j) s_U[mh*20 + j] += U[j];
    }
    __syncthreads();
    {
        int i = t & 15, ms = t >> 4;
        float acc = 0.f;
        for (int m = ms; m < HD; m += 16) {
            const float* cf = Cf + (size_t)m*256 + i*16;
            const float* Um = &s_U[m*20];
            #pragma unroll
            for (int j = 0; j < 16; ++j) acc += Um[j] * cf[j];
        }
        s_red2[ms*16 + i] = acc;
    }
    __syncthreads();
    if (t < 16) {
        float s = 0.f;
        #pragma unroll
        for (int ms = 0; ms < 16; ++ms) s += s_red2[ms*16 + t];
        atomicAdd(out + (size_t)za*CHN + t, s);
    }
}

// ---------------------------------------------------------------------------
extern "C" void kernel_launch(void* const* d_in, const int* in_sizes, int n_in,
                              void* d_out, int out_size, void* d_ws, size_t ws_size,
                              hipStream_t stream) {
    const float* f   = (const float*)d_in[0];
    const float* xyz = (const float*)d_in[1];
    const float* Wq  = (const float*)d_in[2];
    const float* K0  = (const float*)d_in[3];
    const float* K1  = (const float*)d_in[4];
    const float* Kf  = (const float*)d_in[5];
    const float* V0  = (const float*)d_in[6];
    const float* Vf  = (const float*)d_in[7];
    const float* C0  = (const float*)d_in[8];
    const float* C1  = (const float*)d_in[9];
    const float* Cf  = (const float*)d_in[10];
    float* out = (float*)d_out;

    // workspace: TK2 | TC2 | TV2 (float2 tables) | attn_h
    float2* TK2    = (float2*)d_ws;
    float2* TC2    = TK2 + (size_t)NH*G*HD;
    float2* TV2    = TC2 + (size_t)G*HD;
    float*  attn_h = (float*)(TV2 + (size_t)NH*G*HD);

    build_tables<<<160,      128, 0, stream>>>(K0, K1, C0, C1, V0,
                                               (float*)TK2, (float*)TC2,
                                               (float*)TV2, out);
    fused_attn  <<<Z*NH*NPT, 256, 0, stream>>>(f, xyz, Wq, Kf, Vf, TK2, TV2, attn_h);
    conv_kernel <<<Z*NPT*2,  256, 0, stream>>>(xyz, TC2, Cf, attn_h, out);
}